// Round 10
// baseline (230.629 us; speedup 1.0000x reference)
//
#include <hip/hip_runtime.h>

#define NN 50000
#define NE 800000
#define FD 128
#define KH 384
#define NU 256
#define NG 64
#define MAXDEG 64
#define NB 98          // dst buckets of 512 nodes
#define BCAP 10240     // per-bucket capacity
#define EPB 4096       // edges per k_bin block
#define LDA 136        // padded bf16 row (272 B) for GEMM A operands
#define LDH 400        // padded fp8 row (400 B) for H-concat

typedef __attribute__((__ext_vector_type__(8))) short short8;
typedef __attribute__((__ext_vector_type__(4))) float f32x4;
typedef __attribute__((__ext_vector_type__(2))) float f32x2;

// ---- ws layout (bytes, 16B-aligned) ----
#define OFF_POS   0u           // NB int (+pad)         512     [memset]
#define OFF_G     512u         // 64*256 f32            65536   [memset]
#define OFF_CNT   66048u       // 50048 int             200192
#define OFF_BE    266240u      // NB*BCAP u32           4014080
#define OFF_COL   4280320u     // 50048*64 u16          6406144
#define OFF_DINV  10686464u    // 50048 f32             200192
#define OFF_XBF   10886656u    // 50048*272B bf16pad    13613056
#define OFF_XB2   24499712u    // 50048*272B            13613056
#define OFF_XB3   38112768u    // 50048*272B            13613056
#define OFF_H8    51725824u    // 50048*128 fp8         6406144
#define OFF_H8C   58131968u    // 50048*400B fp8pad     20019200
#define OFF_HH    78151168u    // 50048 f32             200192
#define OFF_WR    78351360u    // 3*16384 ushort        98304
#define OFF_SBR   78449664u    // 12*256*32 fp8         98304
#define OFF_SS    78547968u    // 256 f32               1024   -> total 78548992

__device__ __forceinline__ float b2f(ushort h){
  union { unsigned u; float f; } c; c.u = ((unsigned)h) << 16; return c.f;
}
__device__ __forceinline__ ushort f2b(float f){
  union { float f; unsigned u; } c; c.f = f;
  unsigned u = c.u;
  return (ushort)((u + 0x7fffu + ((u >> 16) & 1u)) >> 16);
}

// async global -> LDS: lds dest wave-uniform base; HW adds lane*16
__device__ __forceinline__ void gl16(const void* g, void* l){
  __builtin_amdgcn_global_load_lds((const __attribute__((address_space(1))) void*)g,
                                   (__attribute__((address_space(3))) void*)l, 16, 0, 0);
}

// x f32 [50000][128] -> padded bf16 rows of 136 ushorts
__global__ void k_convert(const float* __restrict__ s, ushort4* __restrict__ d, int n4){
  int i = blockIdx.x * blockDim.x + threadIdx.x;
  if (i >= n4) return;
  int r = i >> 5, q = i & 31;
  float4 v = reinterpret_cast<const float4*>(s)[i];
  ushort4 o; o.x = f2b(v.x); o.y = f2b(v.y); o.z = f2b(v.z); o.w = f2b(v.w);
  d[r * 34 + q] = o;
}

// S f32 [256][384] -> fp8 frag-contiguous: byte idx = kp*8192 + c*32 + k8*8 + b
__global__ void k_s8r(const float* __restrict__ S, unsigned* __restrict__ d){
  int tid = blockIdx.x * blockDim.x + threadIdx.x;   // 24576 = 256 * 96
  int c = tid / 96, kq = tid % 96;
  int k0 = kq * 4;
  float4 v = *reinterpret_cast<const float4*>(S + (size_t)c * KH + k0);
  int p = __builtin_amdgcn_cvt_pk_fp8_f32(v.x, v.y, 0, false);
  p = __builtin_amdgcn_cvt_pk_fp8_f32(v.z, v.w, p, true);
  int kp = k0 >> 5, k8 = (k0 >> 3) & 3;
  d[(kp * 8192 + c * 32 + k8 * 8 + (k0 & 7)) >> 2] = (unsigned)p;
}

// W f32 [128][128] (k,n) -> bf16 frag-contiguous: ushort idx = kp*4096 + n*32 + k8*8 + b
__global__ void k_twr(const float* __restrict__ W, ushort* __restrict__ Wr){
  int n = blockIdx.x, k = threadIdx.x;
  Wr[(k >> 5) * 4096 + n * 32 + ((k >> 3) & 3) * 8 + (k & 7)] = f2b(W[k * FD + n]);
}

// phase A: bin edges by dst>>9, dense bucket appends
__global__ __launch_bounds__(256) void k_bin(const int* __restrict__ ei,
                                             int* __restrict__ bucketPos,
                                             unsigned* __restrict__ be){
  __shared__ int hist[NB], base[NB], off[NB];
  int t = threadIdx.x;
  for (int i = t; i < NB; i += 256) hist[i] = 0;
  __syncthreads();
  int e0 = blockIdx.x * EPB;
  int e1 = min(e0 + EPB, NE);
  for (int e = e0 + t; e < e1; e += 256)
    atomicAdd(&hist[ei[NE + e] >> 9], 1);
  __syncthreads();
  for (int i = t; i < NB; i += 256){
    base[i] = atomicAdd(&bucketPos[i], hist[i]);
    off[i] = 0;
  }
  __syncthreads();
  for (int e = e0 + t; e < e1; e += 256){
    int d = ei[NE + e], s = ei[e];
    int b = d >> 9;
    int p = base[b] + atomicAdd(&off[b], 1);
    if (p < BCAP) be[(size_t)b * BCAP + p] = ((unsigned)(d & 511) << 16) | (unsigned)s;
  }
}

// phase B: one block per bucket; LDS degree counters; L2-local col scatter.
// Also emits cnt and dinv.
__global__ __launch_bounds__(256) void k_build(const int* __restrict__ bucketPos,
                                               const unsigned* __restrict__ be,
                                               int* __restrict__ cnt,
                                               ushort* __restrict__ col,
                                               float* __restrict__ dinv){
  __shared__ int lcnt[512];
  int t = threadIdx.x, b = blockIdx.x;
  for (int i = t; i < 512; i += 256) lcnt[i] = 0;
  __syncthreads();
  int nE = min(bucketPos[b], BCAP);
  const unsigned* bb = be + (size_t)b * BCAP;
  for (int i = t; i < nE; i += 256){
    unsigned u = bb[i];
    int dl = u >> 16, s = u & 0xffffu;
    int pos = atomicAdd(&lcnt[dl], 1);
    if (pos < MAXDEG) col[(size_t)(b * 512 + dl) * MAXDEG + pos] = (ushort)s;
  }
  __syncthreads();
  for (int i = t; i < 512; i += 256){
    int n = b * 512 + i;
    if (n < NN){
      cnt[n] = lcnt[i];
      dinv[n] = rsqrtf((float)(lcnt[i] + 1));
    }
  }
}

// Layer GEMM: C8[M][128] = fp8( rs[r] * (A[M][128] @ W^T) )
// tile 64r x 128c, K=128 whole-tile in LDS; one barrier per block.
__global__ __launch_bounds__(256) void k_gemm(
    const ushort* __restrict__ A,              // padded rows of LDA ushorts
    const ushort* __restrict__ Wr,             // frag-contiguous [4][128][32]
    unsigned char* __restrict__ C8, int M,
    const float* __restrict__ rs){
  __shared__ __align__(16) ushort Al[64 * LDA];   // 17408 B
  const int t = threadIdx.x;
  const int lane = t & 63, w = t >> 6;
  const int wM = w >> 1, wN = w & 1;
  const int ln = lane & 15, hi = lane >> 4;
  const int mBase = blockIdx.x * 64;

  const char* Asrc = (const char*)(A + (size_t)mBase * LDA);
  #pragma unroll
  for (int j = 0; j < 4; ++j){
    int base = w * 1024 + j * 4096;
    gl16(Asrc + base + lane * 16, (char*)Al + base);
  }
  if (w == 0) gl16(Asrc + 16384 + lane * 16, (char*)Al + 16384);
  __syncthreads();

  f32x4 acc[2][4];
  #pragma unroll
  for (int i = 0; i < 2; ++i)
    #pragma unroll
    for (int j = 0; j < 4; ++j) acc[i][j] = (f32x4){0.f, 0.f, 0.f, 0.f};

  #pragma unroll
  for (int kp = 0; kp < 4; ++kp){
    short8 a[2], b[4];
    #pragma unroll
    for (int fm = 0; fm < 2; ++fm)
      a[fm] = *reinterpret_cast<const short8*>(
          (const char*)Al + (wM * 32 + fm * 16 + ln) * 272 + kp * 64 + hi * 16);
    #pragma unroll
    for (int fn = 0; fn < 4; ++fn)
      b[fn] = *reinterpret_cast<const short8*>(
          Wr + kp * 4096 + (wN * 64 + fn * 16 + ln) * 32 + hi * 8);
    #pragma unroll
    for (int fm = 0; fm < 2; ++fm)
      #pragma unroll
      for (int fn = 0; fn < 4; ++fn)
        acc[fm][fn] = __builtin_amdgcn_mfma_f32_16x16x32_bf16(a[fm], b[fn], acc[fm][fn], 0, 0, 0);
  }
  #pragma unroll
  for (int fm = 0; fm < 2; ++fm){
    int r0 = mBase + wM * 32 + fm * 16 + hi * 4;
    float rsv[4] = {0.f, 0.f, 0.f, 0.f};
    #pragma unroll
    for (int j = 0; j < 4; ++j) if (r0 + j < M) rsv[j] = rs[r0 + j];
    #pragma unroll
    for (int fn = 0; fn < 4; ++fn){
      int cg = wN * 64 + fn * 16 + ln;
      f32x4 v = acc[fm][fn];
      int p01 = __builtin_amdgcn_cvt_pk_fp8_f32(v[0] * rsv[0], v[1] * rsv[1], 0, false);
      int p23 = __builtin_amdgcn_cvt_pk_fp8_f32(v[2] * rsv[2], v[3] * rsv[3], 0, false);
      if (r0     < M) C8[(size_t)(r0    ) * FD + cg] = (unsigned char)(p01);
      if (r0 + 1 < M) C8[(size_t)(r0 + 1) * FD + cg] = (unsigned char)(p01 >> 8);
      if (r0 + 2 < M) C8[(size_t)(r0 + 2) * FD + cg] = (unsigned char)(p23);
      if (r0 + 3 < M) C8[(size_t)(r0 + 3) * FD + cg] = (unsigned char)(p23 >> 8);
    }
  }
}

// Wave-autonomous fused SOM: each wave owns 32 rows x 256 units.
// No LDS, no barriers. 391 blocks x 256 thr = 1564 waves.
__global__ __launch_bounds__(256, 2) void k_gsom(
    const unsigned char* __restrict__ A8,   // h8c padded rows of LDH
    const unsigned char* __restrict__ Br,   // Sb8r [12][256][32]
    const float* __restrict__ ss, const float* __restrict__ hh,
    const int* __restrict__ batch, float* __restrict__ G, int M){
  const int lane = threadIdx.x & 63, w = threadIdx.x >> 6;
  const int ln = lane & 15, hi = lane >> 4;
  const int gw = blockIdx.x * 4 + w;
  const int rbase = gw * 32;

  float ssr[16];
  #pragma unroll
  for (int fn = 0; fn < 16; ++fn) ssr[fn] = ss[fn * 16 + ln];

  f32x4 acc0[16], acc1[16];
  #pragma unroll
  for (int i = 0; i < 16; ++i){
    acc0[i] = (f32x4){0.f,0.f,0.f,0.f};
    acc1[i] = (f32x4){0.f,0.f,0.f,0.f};
  }

  const unsigned char* Arow0 = A8 + (size_t)(rbase + ln) * LDH + hi * 8;
  const unsigned char* Arow1 = Arow0 + 16 * LDH;
  #pragma unroll
  for (int kp = 0; kp < 12; ++kp){
    long av0 = *reinterpret_cast<const long*>(Arow0 + kp * 32);
    long av1 = *reinterpret_cast<const long*>(Arow1 + kp * 32);
    #pragma unroll
    for (int fn = 0; fn < 16; ++fn){
      long bv = *reinterpret_cast<const long*>(Br + kp * 8192 + (fn * 16 + ln) * 32 + hi * 8);
      acc0[fn] = __builtin_amdgcn_mfma_f32_16x16x32_fp8_fp8(av0, bv, acc0[fn], 0, 0, 0);
      acc1[fn] = __builtin_amdgcn_mfma_f32_16x16x32_fp8_fp8(av1, bv, acc1[fn], 0, 0, 0);
    }
  }

  // argmin per (fm, j): in-lane over 16 fn, then 16-lane shuffle reduce
  float hs_l[2][4]; int wb_l[2][4];
  #pragma unroll
  for (int fm = 0; fm < 2; ++fm){
    #pragma unroll
    for (int j = 0; j < 4; ++j){
      float mv = 3.4e38f; int mi = 0;
      #pragma unroll
      for (int fn = 0; fn < 16; ++fn){
        float v = ssr[fn] - 2.f * (fm ? acc1[fn][j] : acc0[fn][j]);
        int c = fn * 16 + ln;
        if (v < mv || (v == mv && c < mi)){ mv = v; mi = c; }
      }
      #pragma unroll
      for (int m = 1; m < 16; m <<= 1){
        float ov = __shfl_xor(mv, m);
        int   oi = __shfl_xor(mi, m);
        if (ov < mv || (ov == mv && oi < mi)){ mv = ov; mi = oi; }
      }
      int r = rbase + fm * 16 + hi * 4 + j;
      if (r < M){
        float d2 = fmaxf(hh[r] + mv, 0.f);
        hs_l[fm][j] = __expf(-sqrtf(d2));
        wb_l[fm][j] = mi | (batch[r] << 8);
      } else { hs_l[fm][j] = 0.f; wb_l[fm][j] = -1; }
    }
  }

  // gaussian over the wave's 32 rows via register broadcast (no LDS)
  float g0 = 0.f, g1 = 0.f, g2 = 0.f, g3 = 0.f;
  int curb = -1;
  int c0 = lane * 4;
  float cx = (float)(c0 >> 4);
  #pragma unroll
  for (int rr = 0; rr < 32; ++rr){
    const int fm = rr >> 4, sj = rr & 3, shi = (rr >> 2) & 3;
    int   wb = __shfl(wb_l[fm][sj], shi * 16);
    float hs = __shfl(hs_l[fm][sj], shi * 16);
    if (wb >= 0){
      int b = wb >> 8, win = wb & 255;
      if (b != curb){
        if (curb >= 0){
          atomicAdd(&G[curb * NU + c0    ], g0);
          atomicAdd(&G[curb * NU + c0 + 1], g1);
          atomicAdd(&G[curb * NU + c0 + 2], g2);
          atomicAdd(&G[curb * NU + c0 + 3], g3);
          g0 = g1 = g2 = g3 = 0.f;
        }
        curb = b;
      }
      float wi = (float)(win >> 4), wj = (float)(win & 15);
      float dx = cx - wi;
      float ex = hs * __expf(-dx * dx * 0.125f);
      float dy0 = (float)((c0    ) & 15) - wj;
      float dy1 = (float)((c0 + 1) & 15) - wj;
      float dy2 = (float)((c0 + 2) & 15) - wj;
      float dy3 = (float)((c0 + 3) & 15) - wj;
      g0 += ex * __expf(-dy0 * dy0 * 0.125f);
      g1 += ex * __expf(-dy1 * dy1 * 0.125f);
      g2 += ex * __expf(-dy2 * dy2 * 0.125f);
      g3 += ex * __expf(-dy3 * dy3 * 0.125f);
    }
  }
  if (curb >= 0){
    atomicAdd(&G[curb * NU + c0    ], g0);
    atomicAdd(&G[curb * NU + c0 + 1], g1);
    atomicAdd(&G[curb * NU + c0 + 2], g2);
    atomicAdd(&G[curb * NU + c0 + 3], g3);
  }
}

// Half-feature aggregation pass: group (16 lanes) owns one node, lane owns
// 4 features of the 64-feature half. Touched gather lines per pass = 3.2 MB
// (L2-resident). 8 neighbor rows in flight per group (32/wave).
__global__ __launch_bounds__(256) void k_agg(
    const unsigned char* __restrict__ hs8, const float* __restrict__ dinv,
    const int* __restrict__ cnt, const ushort* __restrict__ col,
    const float* __restrict__ bias, ushort* __restrict__ xn,
    unsigned char* __restrict__ h8c, int cOff,
    float* __restrict__ hh, int half, int first){
  const int lane = threadIdx.x & 63, w = threadIdx.x >> 6;
  const int g = lane >> 4, ln = lane & 15;
  const int n = (blockIdx.x * 4 + w) * 4 + g;       // 3125 blocks x 16 nodes
  if (n >= NN) return;
  const int fi = half * 64 + ln * 4;                // feature index (and byte off)

  unsigned sv = *reinterpret_cast<const unsigned*>(hs8 + (size_t)n * FD + fi);
  f32x2 a0 = __builtin_amdgcn_cvt_pk_f32_fp8((int)sv, false);
  f32x2 a1 = __builtin_amdgcn_cvt_pk_f32_fp8((int)sv, true );

  int ne = cnt[n]; if (ne > MAXDEG) ne = MAXDEG;
  const ushort* cl = col + (size_t)n * MAXDEG;
  for (int j = 0; j < ne; j += 8){
    int s[8]; float wq[8];
    #pragma unroll
    for (int q = 0; q < 8; ++q){
      int i = j + q;
      s[q] = n; wq[q] = 0.f;
      if (i < ne){ s[q] = cl[i]; wq[q] = 1.f; }
    }
    unsigned r[8];
    #pragma unroll
    for (int q = 0; q < 8; ++q)
      r[q] = *reinterpret_cast<const unsigned*>(hs8 + (size_t)s[q] * FD + fi);
    #pragma unroll
    for (int q = 0; q < 8; ++q){
      f32x2 ww = {wq[q], wq[q]};
      a0 += __builtin_amdgcn_cvt_pk_f32_fp8((int)r[q], false) * ww;
      a1 += __builtin_amdgcn_cvt_pk_f32_fp8((int)r[q], true ) * ww;
    }
  }
  float di = dinv[n];
  float v0 = a0[0] * di + bias[fi    ];
  float v1 = a0[1] * di + bias[fi + 1];
  float v2 = a1[0] * di + bias[fi + 2];
  float v3 = a1[1] * di + bias[fi + 3];
  v0 = v0 > 0.f ? v0 : 0.01f * v0;
  v1 = v1 > 0.f ? v1 : 0.01f * v1;
  v2 = v2 > 0.f ? v2 : 0.01f * v2;
  v3 = v3 > 0.f ? v3 : 0.01f * v3;
  float ssq = v0 * v0 + v1 * v1 + v2 * v2 + v3 * v3;

  ushort4 o; o.x = f2b(v0); o.y = f2b(v1); o.z = f2b(v2); o.w = f2b(v3);
  *reinterpret_cast<ushort4*>(xn + (size_t)n * LDA + fi) = o;
  int p = __builtin_amdgcn_cvt_pk_fp8_f32(v0, v1, 0, false);
  p = __builtin_amdgcn_cvt_pk_fp8_f32(v2, v3, p, true);
  *reinterpret_cast<unsigned*>(h8c + (size_t)n * LDH + cOff + fi) = (unsigned)p;

  #pragma unroll
  for (int m = 1; m < 16; m <<= 1) ssq += __shfl_xor(ssq, m);
  if (ln == 0){
    if (first) hh[n] = ssq;
    else       hh[n] += ssq;
  }
}

__global__ void k_ss(const float* __restrict__ S, float* __restrict__ ss){
  int u = blockIdx.x, lane = threadIdx.x;
  const float* p = S + (size_t)u * KH + lane * 6;
  float s = 0.f;
  #pragma unroll
  for (int j = 0; j < 6; ++j){ float v = p[j]; s += v * v; }
  #pragma unroll
  for (int o = 32; o; o >>= 1) s += __shfl_down(s, o);
  if (lane == 0) ss[u] = s;
}

__global__ void k_out(const float* __restrict__ G, const float* __restrict__ lw,
                      const float* __restrict__ lb, float* __restrict__ out){
  int b = blockIdx.x, lane = threadIdx.x;
  float s = 0.f;
  #pragma unroll
  for (int j = 0; j < 4; ++j) s += G[b * NU + lane * 4 + j] * lw[lane * 4 + j];
  #pragma unroll
  for (int o = 32; o; o >>= 1) s += __shfl_down(s, o);
  if (lane == 0) out[b] = 1.f / (1.f + __expf(-(s + lb[0])));
}

extern "C" void kernel_launch(void* const* d_in, const int* in_sizes, int n_in,
                              void* d_out, int out_size, void* d_ws, size_t ws_size,
                              hipStream_t stream){
  const float* x   = (const float*)d_in[0];
  const int*   ei  = (const int*)d_in[1];
  const int*   bat = (const int*)d_in[2];
  const float* W1  = (const float*)d_in[3];
  const float* b1  = (const float*)d_in[4];
  const float* W2  = (const float*)d_in[5];
  const float* b2  = (const float*)d_in[6];
  const float* W3  = (const float*)d_in[7];
  const float* b3  = (const float*)d_in[8];
  const float* S   = (const float*)d_in[9];
  const float* lw  = (const float*)d_in[10];
  const float* lb  = (const float*)d_in[11];
  float* out = (float*)d_out;
  char* w = (char*)d_ws;

  int*      pos  = (int*)     (w + OFF_POS);
  float*    G    = (float*)   (w + OFF_G);
  int*      cnt  = (int*)     (w + OFF_CNT);
  unsigned* be   = (unsigned*)(w + OFF_BE);
  ushort*   col  = (ushort*)  (w + OFF_COL);
  float*    dinv = (float*)   (w + OFF_DINV);
  ushort*   xbf  = (ushort*)  (w + OFF_XBF);
  ushort*   xb2  = (ushort*)  (w + OFF_XB2);
  ushort*   xb3  = (ushort*)  (w + OFF_XB3);
  unsigned char* h8  = (unsigned char*)(w + OFF_H8);
  unsigned char* h8c = (unsigned char*)(w + OFF_H8C);
  float*    hh   = (float*)   (w + OFF_HH);
  ushort*   Wr   = (ushort*)  (w + OFF_WR);
  unsigned char* sbr = (unsigned char*)(w + OFF_SBR);
  float*    ss   = (float*)   (w + OFF_SS);

  hipMemsetAsync(w, 0, 66048, stream);                      // pos + G

  k_convert<<<6250, 256, 0, stream>>>(x, (ushort4*)xbf, 1600000);
  k_s8r<<<96, 256, 0, stream>>>(S, (unsigned*)sbr);
  k_twr<<<128, 128, 0, stream>>>(W1, Wr);
  k_twr<<<128, 128, 0, stream>>>(W2, Wr + 16384);
  k_twr<<<128, 128, 0, stream>>>(W3, Wr + 32768);

  k_bin<<<196, 256, 0, stream>>>(ei, pos, be);
  k_build<<<NB, 256, 0, stream>>>(pos, be, cnt, col, dinv);

  dim3 blk(256);
  // layer 1
  k_gemm<<<782, blk, 0, stream>>>(xbf, Wr, h8, NN, dinv);
  k_agg<<<3125, 256, 0, stream>>>(h8, dinv, cnt, col, b1, xb2, h8c, 0, hh, 0, 1);
  k_agg<<<3125, 256, 0, stream>>>(h8, dinv, cnt, col, b1, xb2, h8c, 0, hh, 1, 0);
  // layer 2
  k_gemm<<<782, blk, 0, stream>>>(xb2, Wr + 16384, h8, NN, dinv);
  k_agg<<<3125, 256, 0, stream>>>(h8, dinv, cnt, col, b2, xb3, h8c, 128, hh, 0, 0);
  k_agg<<<3125, 256, 0, stream>>>(h8, dinv, cnt, col, b2, xb3, h8c, 128, hh, 1, 0);
  // layer 3 (bf16 output slot reused; unused afterwards)
  k_gemm<<<782, blk, 0, stream>>>(xb3, Wr + 32768, h8, NN, dinv);
  k_agg<<<3125, 256, 0, stream>>>(h8, dinv, cnt, col, b3, xbf, h8c, 256, hh, 0, 0);
  k_agg<<<3125, 256, 0, stream>>>(h8, dinv, cnt, col, b3, xbf, h8c, 256, hh, 1, 0);

  k_ss<<<256, 64, 0, stream>>>(S, ss);
  // wave-autonomous fused SOM (no LDS, no barriers)
  k_gsom<<<391, blk, 0, stream>>>(h8c, sbr, ss, hh, bat, G, NN);
  k_out<<<64, 64, 0, stream>>>(G, lw, lb, out);
}

// Round 11
// 192.914 us; speedup vs baseline: 1.1955x; 1.1955x over previous
//
#include <hip/hip_runtime.h>

#define NN 50000
#define NE 800000
#define FD 128
#define KH 384
#define NU 256
#define NG 64
#define MAXDEG 64
#define NB 98          // dst buckets of 512 nodes
#define BCAP 10240     // per-bucket capacity
#define EPB 4096       // edges per k_bin block
#define LDA 136        // padded bf16 row (272 B) for GEMM A operands
#define LDH 400        // padded fp8 row (400 B) for H-concat

typedef __attribute__((__ext_vector_type__(8))) short short8;
typedef __attribute__((__ext_vector_type__(4))) float f32x4;
typedef __attribute__((__ext_vector_type__(2))) float f32x2;

// ---- ws layout (bytes, 16B-aligned) ----
#define OFF_POS   0u           // NB int (+pad)         512     [memset]
#define OFF_G     512u         // 64*256 f32            65536   [memset]
#define OFF_CNT   66048u       // 50048 int             200192
#define OFF_BE    266240u      // NB*BCAP u32           4014080
#define OFF_COL   4280320u     // 50048*64 u16          6406144
#define OFF_DINV  10686464u    // 50048 f32             200192
#define OFF_XBF   10886656u    // 50048*272B bf16pad    13613056
#define OFF_XB2   24499712u    // 50048*272B            13613056
#define OFF_XB3   38112768u    // 50048*272B            13613056
#define OFF_H8    51725824u    // 50048*128 fp8         6406144
#define OFF_H8C   58131968u    // 50048*400B fp8pad     20019200
#define OFF_HH    78151168u    // 50048 f32             200192
#define OFF_WR    78351360u    // 3*16384 ushort        98304
#define OFF_SBR   78449664u    // 12*256*32 fp8         98304
#define OFF_SS    78547968u    // 256 f32               1024   -> total 78548992

__device__ __forceinline__ float b2f(ushort h){
  union { unsigned u; float f; } c; c.u = ((unsigned)h) << 16; return c.f;
}
__device__ __forceinline__ ushort f2b(float f){
  union { float f; unsigned u; } c; c.f = f;
  unsigned u = c.u;
  return (ushort)((u + 0x7fffu + ((u >> 16) & 1u)) >> 16);
}

// async global -> LDS: lds dest wave-uniform base; HW adds lane*16
__device__ __forceinline__ void gl16(const void* g, void* l){
  __builtin_amdgcn_global_load_lds((const __attribute__((address_space(1))) void*)g,
                                   (__attribute__((address_space(3))) void*)l, 16, 0, 0);
}

// x f32 [50000][128] -> padded bf16 rows of 136 ushorts
__global__ void k_convert(const float* __restrict__ s, ushort4* __restrict__ d, int n4){
  int i = blockIdx.x * blockDim.x + threadIdx.x;
  if (i >= n4) return;
  int r = i >> 5, q = i & 31;
  float4 v = reinterpret_cast<const float4*>(s)[i];
  ushort4 o; o.x = f2b(v.x); o.y = f2b(v.y); o.z = f2b(v.z); o.w = f2b(v.w);
  d[r * 34 + q] = o;
}

// S f32 [256][384] -> fp8 frag-contiguous: byte idx = kp*8192 + c*32 + k8*8 + b
__global__ void k_s8r(const float* __restrict__ S, unsigned* __restrict__ d){
  int tid = blockIdx.x * blockDim.x + threadIdx.x;   // 24576 = 256 * 96
  int c = tid / 96, kq = tid % 96;
  int k0 = kq * 4;
  float4 v = *reinterpret_cast<const float4*>(S + (size_t)c * KH + k0);
  int p = __builtin_amdgcn_cvt_pk_fp8_f32(v.x, v.y, 0, false);
  p = __builtin_amdgcn_cvt_pk_fp8_f32(v.z, v.w, p, true);
  int kp = k0 >> 5, k8 = (k0 >> 3) & 3;
  d[(kp * 8192 + c * 32 + k8 * 8 + (k0 & 7)) >> 2] = (unsigned)p;
}

// W f32 [128][128] (k,n) -> bf16 frag-contiguous: ushort idx = kp*4096 + n*32 + k8*8 + b
__global__ void k_twr(const float* __restrict__ W, ushort* __restrict__ Wr){
  int n = blockIdx.x, k = threadIdx.x;
  Wr[(k >> 5) * 4096 + n * 32 + ((k >> 3) & 3) * 8 + (k & 7)] = f2b(W[k * FD + n]);
}

// phase A: bin edges by dst>>9, dense bucket appends
__global__ __launch_bounds__(256) void k_bin(const int* __restrict__ ei,
                                             int* __restrict__ bucketPos,
                                             unsigned* __restrict__ be){
  __shared__ int hist[NB], base[NB], off[NB];
  int t = threadIdx.x;
  for (int i = t; i < NB; i += 256) hist[i] = 0;
  __syncthreads();
  int e0 = blockIdx.x * EPB;
  int e1 = min(e0 + EPB, NE);
  for (int e = e0 + t; e < e1; e += 256)
    atomicAdd(&hist[ei[NE + e] >> 9], 1);
  __syncthreads();
  for (int i = t; i < NB; i += 256){
    base[i] = atomicAdd(&bucketPos[i], hist[i]);
    off[i] = 0;
  }
  __syncthreads();
  for (int e = e0 + t; e < e1; e += 256){
    int d = ei[NE + e], s = ei[e];
    int b = d >> 9;
    int p = base[b] + atomicAdd(&off[b], 1);
    if (p < BCAP) be[(size_t)b * BCAP + p] = ((unsigned)(d & 511) << 16) | (unsigned)s;
  }
}

// phase B: one block per bucket; LDS degree counters; L2-local col scatter.
// Also emits cnt and dinv.
__global__ __launch_bounds__(256) void k_build(const int* __restrict__ bucketPos,
                                               const unsigned* __restrict__ be,
                                               int* __restrict__ cnt,
                                               ushort* __restrict__ col,
                                               float* __restrict__ dinv){
  __shared__ int lcnt[512];
  int t = threadIdx.x, b = blockIdx.x;
  for (int i = t; i < 512; i += 256) lcnt[i] = 0;
  __syncthreads();
  int nE = min(bucketPos[b], BCAP);
  const unsigned* bb = be + (size_t)b * BCAP;
  for (int i = t; i < nE; i += 256){
    unsigned u = bb[i];
    int dl = u >> 16, s = u & 0xffffu;
    int pos = atomicAdd(&lcnt[dl], 1);
    if (pos < MAXDEG) col[(size_t)(b * 512 + dl) * MAXDEG + pos] = (ushort)s;
  }
  __syncthreads();
  for (int i = t; i < 512; i += 256){
    int n = b * 512 + i;
    if (n < NN){
      cnt[n] = lcnt[i];
      dinv[n] = rsqrtf((float)(lcnt[i] + 1));
    }
  }
}

// Layer GEMM: C8[M][128] = fp8( rs[r] * (A[M][128] @ W^T) )
// tile 64r x 128c, K=128 whole-tile in LDS; one barrier per block.
__global__ __launch_bounds__(256) void k_gemm(
    const ushort* __restrict__ A,              // padded rows of LDA ushorts
    const ushort* __restrict__ Wr,             // frag-contiguous [4][128][32]
    unsigned char* __restrict__ C8, int M,
    const float* __restrict__ rs){
  __shared__ __align__(16) ushort Al[64 * LDA];   // 17408 B
  const int t = threadIdx.x;
  const int lane = t & 63, w = t >> 6;
  const int wM = w >> 1, wN = w & 1;
  const int ln = lane & 15, hi = lane >> 4;
  const int mBase = blockIdx.x * 64;

  const char* Asrc = (const char*)(A + (size_t)mBase * LDA);
  #pragma unroll
  for (int j = 0; j < 4; ++j){
    int base = w * 1024 + j * 4096;
    gl16(Asrc + base + lane * 16, (char*)Al + base);
  }
  if (w == 0) gl16(Asrc + 16384 + lane * 16, (char*)Al + 16384);
  __syncthreads();

  f32x4 acc[2][4];
  #pragma unroll
  for (int i = 0; i < 2; ++i)
    #pragma unroll
    for (int j = 0; j < 4; ++j) acc[i][j] = (f32x4){0.f, 0.f, 0.f, 0.f};

  #pragma unroll
  for (int kp = 0; kp < 4; ++kp){
    short8 a[2], b[4];
    #pragma unroll
    for (int fm = 0; fm < 2; ++fm)
      a[fm] = *reinterpret_cast<const short8*>(
          (const char*)Al + (wM * 32 + fm * 16 + ln) * 272 + kp * 64 + hi * 16);
    #pragma unroll
    for (int fn = 0; fn < 4; ++fn)
      b[fn] = *reinterpret_cast<const short8*>(
          Wr + kp * 4096 + (wN * 64 + fn * 16 + ln) * 32 + hi * 8);
    #pragma unroll
    for (int fm = 0; fm < 2; ++fm)
      #pragma unroll
      for (int fn = 0; fn < 4; ++fn)
        acc[fm][fn] = __builtin_amdgcn_mfma_f32_16x16x32_bf16(a[fm], b[fn], acc[fm][fn], 0, 0, 0);
  }
  #pragma unroll
  for (int fm = 0; fm < 2; ++fm){
    int r0 = mBase + wM * 32 + fm * 16 + hi * 4;
    float rsv[4] = {0.f, 0.f, 0.f, 0.f};
    #pragma unroll
    for (int j = 0; j < 4; ++j) if (r0 + j < M) rsv[j] = rs[r0 + j];
    #pragma unroll
    for (int fn = 0; fn < 4; ++fn){
      int cg = wN * 64 + fn * 16 + ln;
      f32x4 v = acc[fm][fn];
      int p01 = __builtin_amdgcn_cvt_pk_fp8_f32(v[0] * rsv[0], v[1] * rsv[1], 0, false);
      int p23 = __builtin_amdgcn_cvt_pk_fp8_f32(v[2] * rsv[2], v[3] * rsv[3], 0, false);
      if (r0     < M) C8[(size_t)(r0    ) * FD + cg] = (unsigned char)(p01);
      if (r0 + 1 < M) C8[(size_t)(r0 + 1) * FD + cg] = (unsigned char)(p01 >> 8);
      if (r0 + 2 < M) C8[(size_t)(r0 + 2) * FD + cg] = (unsigned char)(p23);
      if (r0 + 3 < M) C8[(size_t)(r0 + 3) * FD + cg] = (unsigned char)(p23 >> 8);
    }
  }
}

// Wave-autonomous fused SOM: each wave owns 32 rows x 256 units.
// No LDS, no barriers. 391 blocks x 256 thr = 1564 waves.
__global__ __launch_bounds__(256, 2) void k_gsom(
    const unsigned char* __restrict__ A8,   // h8c padded rows of LDH
    const unsigned char* __restrict__ Br,   // Sb8r [12][256][32]
    const float* __restrict__ ss, const float* __restrict__ hh,
    const int* __restrict__ batch, float* __restrict__ G, int M){
  const int lane = threadIdx.x & 63, w = threadIdx.x >> 6;
  const int ln = lane & 15, hi = lane >> 4;
  const int gw = blockIdx.x * 4 + w;
  const int rbase = gw * 32;

  float ssr[16];
  #pragma unroll
  for (int fn = 0; fn < 16; ++fn) ssr[fn] = ss[fn * 16 + ln];

  f32x4 acc0[16], acc1[16];
  #pragma unroll
  for (int i = 0; i < 16; ++i){
    acc0[i] = (f32x4){0.f,0.f,0.f,0.f};
    acc1[i] = (f32x4){0.f,0.f,0.f,0.f};
  }

  const unsigned char* Arow0 = A8 + (size_t)(rbase + ln) * LDH + hi * 8;
  const unsigned char* Arow1 = Arow0 + 16 * LDH;
  #pragma unroll
  for (int kp = 0; kp < 12; ++kp){
    long av0 = *reinterpret_cast<const long*>(Arow0 + kp * 32);
    long av1 = *reinterpret_cast<const long*>(Arow1 + kp * 32);
    #pragma unroll
    for (int fn = 0; fn < 16; ++fn){
      long bv = *reinterpret_cast<const long*>(Br + kp * 8192 + (fn * 16 + ln) * 32 + hi * 8);
      acc0[fn] = __builtin_amdgcn_mfma_f32_16x16x32_fp8_fp8(av0, bv, acc0[fn], 0, 0, 0);
      acc1[fn] = __builtin_amdgcn_mfma_f32_16x16x32_fp8_fp8(av1, bv, acc1[fn], 0, 0, 0);
    }
  }

  // argmin per (fm, j): in-lane over 16 fn, then 16-lane shuffle reduce
  float hs_l[2][4]; int wb_l[2][4];
  #pragma unroll
  for (int fm = 0; fm < 2; ++fm){
    #pragma unroll
    for (int j = 0; j < 4; ++j){
      float mv = 3.4e38f; int mi = 0;
      #pragma unroll
      for (int fn = 0; fn < 16; ++fn){
        float v = ssr[fn] - 2.f * (fm ? acc1[fn][j] : acc0[fn][j]);
        int c = fn * 16 + ln;
        if (v < mv || (v == mv && c < mi)){ mv = v; mi = c; }
      }
      #pragma unroll
      for (int m = 1; m < 16; m <<= 1){
        float ov = __shfl_xor(mv, m);
        int   oi = __shfl_xor(mi, m);
        if (ov < mv || (ov == mv && oi < mi)){ mv = ov; mi = oi; }
      }
      int r = rbase + fm * 16 + hi * 4 + j;
      if (r < M){
        float d2 = fmaxf(hh[r] + mv, 0.f);
        hs_l[fm][j] = __expf(-sqrtf(d2));
        wb_l[fm][j] = mi | (batch[r] << 8);
      } else { hs_l[fm][j] = 0.f; wb_l[fm][j] = -1; }
    }
  }

  // gaussian over the wave's 32 rows via register broadcast (no LDS)
  float g0 = 0.f, g1 = 0.f, g2 = 0.f, g3 = 0.f;
  int curb = -1;
  int c0 = lane * 4;
  float cx = (float)(c0 >> 4);
  #pragma unroll
  for (int rr = 0; rr < 32; ++rr){
    const int fm = rr >> 4, sj = rr & 3, shi = (rr >> 2) & 3;
    int   wb = __shfl(wb_l[fm][sj], shi * 16);
    float hs = __shfl(hs_l[fm][sj], shi * 16);
    if (wb >= 0){
      int b = wb >> 8, win = wb & 255;
      if (b != curb){
        if (curb >= 0){
          atomicAdd(&G[curb * NU + c0    ], g0);
          atomicAdd(&G[curb * NU + c0 + 1], g1);
          atomicAdd(&G[curb * NU + c0 + 2], g2);
          atomicAdd(&G[curb * NU + c0 + 3], g3);
          g0 = g1 = g2 = g3 = 0.f;
        }
        curb = b;
      }
      float wi = (float)(win >> 4), wj = (float)(win & 15);
      float dx = cx - wi;
      float ex = hs * __expf(-dx * dx * 0.125f);
      float dy0 = (float)((c0    ) & 15) - wj;
      float dy1 = (float)((c0 + 1) & 15) - wj;
      float dy2 = (float)((c0 + 2) & 15) - wj;
      float dy3 = (float)((c0 + 3) & 15) - wj;
      g0 += ex * __expf(-dy0 * dy0 * 0.125f);
      g1 += ex * __expf(-dy1 * dy1 * 0.125f);
      g2 += ex * __expf(-dy2 * dy2 * 0.125f);
      g3 += ex * __expf(-dy3 * dy3 * 0.125f);
    }
  }
  if (curb >= 0){
    atomicAdd(&G[curb * NU + c0    ], g0);
    atomicAdd(&G[curb * NU + c0 + 1], g1);
    atomicAdd(&G[curb * NU + c0 + 2], g2);
    atomicAdd(&G[curb * NU + c0 + 3], g3);
  }
}

// Aggregation: 16-lane group owns one node entirely (lane = 8 features, 8B).
// 4 nodes/wave, 8 neighbor rows in flight per group = 32 rows (4KB) per wave.
// No cross-group reduction needed.
__global__ __launch_bounds__(256) void k_agg(
    const unsigned char* __restrict__ hs8, const float* __restrict__ dinv,
    const int* __restrict__ cnt, const ushort* __restrict__ col,
    const float* __restrict__ bias, ushort* __restrict__ xn,
    unsigned char* __restrict__ h8c, int cOff,
    float* __restrict__ hh, int first){
  const int lane = threadIdx.x & 63, w = threadIdx.x >> 6;
  const int g = lane >> 4, ln = lane & 15;
  const int n = (blockIdx.x * 4 + w) * 4 + g;       // 3125 blocks x 16 nodes
  if (n >= NN) return;
  const int fi = ln * 8;                            // feature/byte offset

  uint2 sv = *reinterpret_cast<const uint2*>(hs8 + (size_t)n * FD + fi);
  f32x2 p0 = __builtin_amdgcn_cvt_pk_f32_fp8((int)sv.x, false);
  f32x2 p1 = __builtin_amdgcn_cvt_pk_f32_fp8((int)sv.x, true );
  f32x2 p2 = __builtin_amdgcn_cvt_pk_f32_fp8((int)sv.y, false);
  f32x2 p3 = __builtin_amdgcn_cvt_pk_f32_fp8((int)sv.y, true );

  int ne = cnt[n]; if (ne > MAXDEG) ne = MAXDEG;
  const ushort* cl = col + (size_t)n * MAXDEG;
  for (int j = 0; j < ne; j += 8){
    int s[8]; float wq[8];
    #pragma unroll
    for (int q = 0; q < 8; ++q){
      int i = j + q;
      s[q] = n; wq[q] = 0.f;
      if (i < ne){ s[q] = cl[i]; wq[q] = 1.f; }
    }
    uint2 r[8];
    #pragma unroll
    for (int q = 0; q < 8; ++q)
      r[q] = *reinterpret_cast<const uint2*>(hs8 + (size_t)s[q] * FD + fi);
    #pragma unroll
    for (int q = 0; q < 8; ++q){
      f32x2 ww = {wq[q], wq[q]};
      p0 += __builtin_amdgcn_cvt_pk_f32_fp8((int)r[q].x, false) * ww;
      p1 += __builtin_amdgcn_cvt_pk_f32_fp8((int)r[q].x, true ) * ww;
      p2 += __builtin_amdgcn_cvt_pk_f32_fp8((int)r[q].y, false) * ww;
      p3 += __builtin_amdgcn_cvt_pk_f32_fp8((int)r[q].y, true ) * ww;
    }
  }
  float di = dinv[n];
  float vv[8] = {p0[0], p0[1], p1[0], p1[1], p2[0], p2[1], p3[0], p3[1]};
  float ssq = 0.f;
  short8 o;
  #pragma unroll
  for (int k = 0; k < 8; ++k){
    float v = vv[k] * di + bias[fi + k];
    v = v > 0.f ? v : 0.01f * v;
    ssq += v * v;
    vv[k] = v;
    o[k] = (short)f2b(v);
  }
  *reinterpret_cast<short8*>(xn + (size_t)n * LDA + fi) = o;
  int pa = __builtin_amdgcn_cvt_pk_fp8_f32(vv[0], vv[1], 0, false);
  pa = __builtin_amdgcn_cvt_pk_fp8_f32(vv[2], vv[3], pa, true);
  int pb = __builtin_amdgcn_cvt_pk_fp8_f32(vv[4], vv[5], 0, false);
  pb = __builtin_amdgcn_cvt_pk_fp8_f32(vv[6], vv[7], pb, true);
  uint2 pk; pk.x = (unsigned)pa; pk.y = (unsigned)pb;
  *reinterpret_cast<uint2*>(h8c + (size_t)n * LDH + cOff + fi) = pk;
  #pragma unroll
  for (int m = 1; m < 16; m <<= 1) ssq += __shfl_xor(ssq, m);
  if (ln == 0){
    if (first) hh[n] = ssq;
    else       hh[n] += ssq;
  }
}

__global__ void k_ss(const float* __restrict__ S, float* __restrict__ ss){
  int u = blockIdx.x, lane = threadIdx.x;
  const float* p = S + (size_t)u * KH + lane * 6;
  float s = 0.f;
  #pragma unroll
  for (int j = 0; j < 6; ++j){ float v = p[j]; s += v * v; }
  #pragma unroll
  for (int o = 32; o; o >>= 1) s += __shfl_down(s, o);
  if (lane == 0) ss[u] = s;
}

__global__ void k_out(const float* __restrict__ G, const float* __restrict__ lw,
                      const float* __restrict__ lb, float* __restrict__ out){
  int b = blockIdx.x, lane = threadIdx.x;
  float s = 0.f;
  #pragma unroll
  for (int j = 0; j < 4; ++j) s += G[b * NU + lane * 4 + j] * lw[lane * 4 + j];
  #pragma unroll
  for (int o = 32; o; o >>= 1) s += __shfl_down(s, o);
  if (lane == 0) out[b] = 1.f / (1.f + __expf(-(s + lb[0])));
}

extern "C" void kernel_launch(void* const* d_in, const int* in_sizes, int n_in,
                              void* d_out, int out_size, void* d_ws, size_t ws_size,
                              hipStream_t stream){
  const float* x   = (const float*)d_in[0];
  const int*   ei  = (const int*)d_in[1];
  const int*   bat = (const int*)d_in[2];
  const float* W1  = (const float*)d_in[3];
  const float* b1  = (const float*)d_in[4];
  const float* W2  = (const float*)d_in[5];
  const float* b2  = (const float*)d_in[6];
  const float* W3  = (const float*)d_in[7];
  const float* b3  = (const float*)d_in[8];
  const float* S   = (const float*)d_in[9];
  const float* lw  = (const float*)d_in[10];
  const float* lb  = (const float*)d_in[11];
  float* out = (float*)d_out;
  char* w = (char*)d_ws;

  int*      pos  = (int*)     (w + OFF_POS);
  float*    G    = (float*)   (w + OFF_G);
  int*      cnt  = (int*)     (w + OFF_CNT);
  unsigned* be   = (unsigned*)(w + OFF_BE);
  ushort*   col  = (ushort*)  (w + OFF_COL);
  float*    dinv = (float*)   (w + OFF_DINV);
  ushort*   xbf  = (ushort*)  (w + OFF_XBF);
  ushort*   xb2  = (ushort*)  (w + OFF_XB2);
  ushort*   xb3  = (ushort*)  (w + OFF_XB3);
  unsigned char* h8  = (unsigned char*)(w + OFF_H8);
  unsigned char* h8c = (unsigned char*)(w + OFF_H8C);
  float*    hh   = (float*)   (w + OFF_HH);
  ushort*   Wr   = (ushort*)  (w + OFF_WR);
  unsigned char* sbr = (unsigned char*)(w + OFF_SBR);
  float*    ss   = (float*)   (w + OFF_SS);

  hipMemsetAsync(w, 0, 66048, stream);                      // pos + G

  k_convert<<<6250, 256, 0, stream>>>(x, (ushort4*)xbf, 1600000);
  k_s8r<<<96, 256, 0, stream>>>(S, (unsigned*)sbr);
  k_twr<<<128, 128, 0, stream>>>(W1, Wr);
  k_twr<<<128, 128, 0, stream>>>(W2, Wr + 16384);
  k_twr<<<128, 128, 0, stream>>>(W3, Wr + 32768);

  k_bin<<<196, 256, 0, stream>>>(ei, pos, be);
  k_build<<<NB, 256, 0, stream>>>(pos, be, cnt, col, dinv);

  dim3 blk(256);
  // layer 1
  k_gemm<<<782, blk, 0, stream>>>(xbf, Wr, h8, NN, dinv);
  k_agg<<<3125, 256, 0, stream>>>(h8, dinv, cnt, col, b1, xb2, h8c, 0, hh, 1);
  // layer 2
  k_gemm<<<782, blk, 0, stream>>>(xb2, Wr + 16384, h8, NN, dinv);
  k_agg<<<3125, 256, 0, stream>>>(h8, dinv, cnt, col, b2, xb3, h8c, 128, hh, 0);
  // layer 3 (bf16 output slot reused; unused afterwards)
  k_gemm<<<782, blk, 0, stream>>>(xb3, Wr + 32768, h8, NN, dinv);
  k_agg<<<3125, 256, 0, stream>>>(h8, dinv, cnt, col, b3, xbf, h8c, 256, hh, 0);

  k_ss<<<256, 64, 0, stream>>>(S, ss);
  // wave-autonomous fused SOM (no LDS, no barriers)
  k_gsom<<<391, blk, 0, stream>>>(h8c, sbr, ss, hh, bat, G, NN);
  k_out<<<64, 64, 0, stream>>>(G, lw, lb, out);
}

// Round 12
// 172.465 us; speedup vs baseline: 1.3373x; 1.1186x over previous
//
#include <hip/hip_runtime.h>

#define NN 50000
#define NE 800000
#define FD 128
#define KH 384
#define NU 256
#define NG 64
#define MAXDEG 64
#define NB 98          // dst buckets of 512 nodes
#define BCAP 10240     // per-bucket capacity
#define EPB 4096       // edges per k_bin block
#define LDH 400        // padded fp8 row (400 B) for H-concat

typedef __attribute__((__ext_vector_type__(4))) float f32x4;
typedef __attribute__((__ext_vector_type__(2))) float f32x2;

// ---- ws layout (bytes, 16B-aligned) ----
#define OFF_POS   0u           // NB int (+pad)         512     [memset]
#define OFF_G     512u         // 64*256 f32            65536   [memset]
#define OFF_CNT   66048u       // 50048 int             200192
#define OFF_BE    266240u      // NB*BCAP u32           4014080
#define OFF_COL   4280320u     // 50048*64 u16          6406144
#define OFF_DINV  10686464u    // 50048 f32             200192
#define OFF_X8    10886656u    // 50048*128 fp8         6406144
#define OFF_H8    17292800u    // 50048*128 fp8         6406144
#define OFF_H8C   23698944u    // 50048*400B fp8pad     20019200
#define OFF_HH    43718144u    // 50048 f32             200192
#define OFF_W8R   43918336u    // 3*[4][128][32] fp8    49152
#define OFF_SBR   43967488u    // [12][256][32] fp8     98304
#define OFF_SS    44065792u    // 256 f32               1024   -> total 44066816

// Fused prep: x -> fp8 dense; S -> fp8 frag-contiguous; W1..3 -> fp8 frag-contiguous
__global__ __launch_bounds__(256) void k_prep(
    const float* __restrict__ x, unsigned* __restrict__ x8,
    const float* __restrict__ S, unsigned* __restrict__ sbr,
    const float* __restrict__ W1, const float* __restrict__ W2,
    const float* __restrict__ W3, unsigned char* __restrict__ w8r){
  int tid = blockIdx.x * 256 + threadIdx.x;
  if (tid < 1600000){                    // x: 50000*128/4 quads
    float4 v = reinterpret_cast<const float4*>(x)[tid];
    int p = __builtin_amdgcn_cvt_pk_fp8_f32(v.x, v.y, 0, false);
    p = __builtin_amdgcn_cvt_pk_fp8_f32(v.z, v.w, p, true);
    x8[tid] = (unsigned)p;
  } else if (tid < 1624576){             // S: 256*384/4 quads
    int t = tid - 1600000;
    int c = t / 96, k0 = (t % 96) * 4;
    float4 v = *reinterpret_cast<const float4*>(S + (size_t)c * KH + k0);
    int p = __builtin_amdgcn_cvt_pk_fp8_f32(v.x, v.y, 0, false);
    p = __builtin_amdgcn_cvt_pk_fp8_f32(v.z, v.w, p, true);
    sbr[((k0 >> 5) * 8192 + c * 32 + (k0 & 31)) >> 2] = (unsigned)p;
  } else if (tid < 1673728){             // W: 3*128*128 elements
    int t = tid - 1624576;
    int wi = t >> 14, e = t & 16383;
    int k = e >> 7, n = e & 127;
    const float* W = (wi == 0) ? W1 : (wi == 1) ? W2 : W3;
    float v = W[k * FD + n];
    int p = __builtin_amdgcn_cvt_pk_fp8_f32(v, v, 0, false);
    w8r[wi * 16384 + (k >> 5) * 4096 + n * 32 + (k & 31)] = (unsigned char)p;
  }
}

// phase A: bin edges by dst>>9, dense bucket appends
__global__ __launch_bounds__(256) void k_bin(const int* __restrict__ ei,
                                             int* __restrict__ bucketPos,
                                             unsigned* __restrict__ be){
  __shared__ int hist[NB], base[NB], off[NB];
  int t = threadIdx.x;
  for (int i = t; i < NB; i += 256) hist[i] = 0;
  __syncthreads();
  int e0 = blockIdx.x * EPB;
  int e1 = min(e0 + EPB, NE);
  for (int e = e0 + t; e < e1; e += 256)
    atomicAdd(&hist[ei[NE + e] >> 9], 1);
  __syncthreads();
  for (int i = t; i < NB; i += 256){
    base[i] = atomicAdd(&bucketPos[i], hist[i]);
    off[i] = 0;
  }
  __syncthreads();
  for (int e = e0 + t; e < e1; e += 256){
    int d = ei[NE + e], s = ei[e];
    int b = d >> 9;
    int p = base[b] + atomicAdd(&off[b], 1);
    if (p < BCAP) be[(size_t)b * BCAP + p] = ((unsigned)(d & 511) << 16) | (unsigned)s;
  }
}

// phase B: one block per bucket; LDS degree counters; L2-local col scatter.
__global__ __launch_bounds__(256) void k_build(const int* __restrict__ bucketPos,
                                               const unsigned* __restrict__ be,
                                               int* __restrict__ cnt,
                                               ushort* __restrict__ col,
                                               float* __restrict__ dinv){
  __shared__ int lcnt[512];
  int t = threadIdx.x, b = blockIdx.x;
  for (int i = t; i < 512; i += 256) lcnt[i] = 0;
  __syncthreads();
  int nE = min(bucketPos[b], BCAP);
  const unsigned* bb = be + (size_t)b * BCAP;
  for (int i = t; i < nE; i += 256){
    unsigned u = bb[i];
    int dl = u >> 16, s = u & 0xffffu;
    int pos = atomicAdd(&lcnt[dl], 1);
    if (pos < MAXDEG) col[(size_t)(b * 512 + dl) * MAXDEG + pos] = (ushort)s;
  }
  __syncthreads();
  for (int i = t; i < 512; i += 256){
    int n = b * 512 + i;
    if (n < NN){
      cnt[n] = lcnt[i];
      dinv[n] = rsqrtf((float)(lcnt[i] + 1));
    }
  }
}

// Wave-autonomous fp8 layer GEMM: wave owns 32 rows x 128 cols, K=128.
// A per-lane from global (L1-resident slice), W frag-contig [4][128][32] from L2.
// Output: h8[r][c] = fp8( dinv[r] * dot )   (dense 128B rows)
__global__ __launch_bounds__(256, 2) void k_gemm8(
    const unsigned char* __restrict__ A8, int strideA,
    const unsigned char* __restrict__ W8,
    unsigned char* __restrict__ C8,
    const float* __restrict__ dinv){
  const int lane = threadIdx.x & 63, w = threadIdx.x >> 6;
  const int ln = lane & 15, hi = lane >> 4;
  const int rbase = (blockIdx.x * 4 + w) * 32;

  f32x4 acc0[8], acc1[8];
  #pragma unroll
  for (int i = 0; i < 8; ++i){
    acc0[i] = (f32x4){0.f,0.f,0.f,0.f};
    acc1[i] = (f32x4){0.f,0.f,0.f,0.f};
  }
  const unsigned char* Ar0 = A8 + (size_t)(rbase + ln) * strideA + hi * 8;
  const unsigned char* Ar1 = Ar0 + (size_t)16 * strideA;
  #pragma unroll
  for (int kp = 0; kp < 4; ++kp){
    long av0 = *reinterpret_cast<const long*>(Ar0 + kp * 32);
    long av1 = *reinterpret_cast<const long*>(Ar1 + kp * 32);
    #pragma unroll
    for (int fn = 0; fn < 8; ++fn){
      long bv = *reinterpret_cast<const long*>(W8 + kp * 4096 + (fn * 16 + ln) * 32 + hi * 8);
      acc0[fn] = __builtin_amdgcn_mfma_f32_16x16x32_fp8_fp8(av0, bv, acc0[fn], 0, 0, 0);
      acc1[fn] = __builtin_amdgcn_mfma_f32_16x16x32_fp8_fp8(av1, bv, acc1[fn], 0, 0, 0);
    }
  }
  #pragma unroll
  for (int fm = 0; fm < 2; ++fm){
    #pragma unroll
    for (int j = 0; j < 4; ++j){
      int r = rbase + fm * 16 + hi * 4 + j;
      float di = dinv[r];
      #pragma unroll
      for (int fn = 0; fn < 8; ++fn){
        float v = (fm ? acc1[fn][j] : acc0[fn][j]) * di;
        int p = __builtin_amdgcn_cvt_pk_fp8_f32(v, v, 0, false);
        C8[(size_t)r * FD + fn * 16 + ln] = (unsigned char)p;
      }
    }
  }
}

// Wave-autonomous fused SOM: each wave owns 32 rows x 256 units. No LDS/barriers.
__global__ __launch_bounds__(256, 2) void k_gsom(
    const unsigned char* __restrict__ A8,   // h8c padded rows of LDH
    const unsigned char* __restrict__ Br,   // Sb8r [12][256][32]
    const float* __restrict__ ss, const float* __restrict__ hh,
    const int* __restrict__ batch, float* __restrict__ G, int M){
  const int lane = threadIdx.x & 63, w = threadIdx.x >> 6;
  const int ln = lane & 15, hi = lane >> 4;
  const int gw = blockIdx.x * 4 + w;
  const int rbase = gw * 32;

  float ssr[16];
  #pragma unroll
  for (int fn = 0; fn < 16; ++fn) ssr[fn] = ss[fn * 16 + ln];

  f32x4 acc0[16], acc1[16];
  #pragma unroll
  for (int i = 0; i < 16; ++i){
    acc0[i] = (f32x4){0.f,0.f,0.f,0.f};
    acc1[i] = (f32x4){0.f,0.f,0.f,0.f};
  }

  const unsigned char* Arow0 = A8 + (size_t)(rbase + ln) * LDH + hi * 8;
  const unsigned char* Arow1 = Arow0 + 16 * LDH;
  #pragma unroll
  for (int kp = 0; kp < 12; ++kp){
    long av0 = *reinterpret_cast<const long*>(Arow0 + kp * 32);
    long av1 = *reinterpret_cast<const long*>(Arow1 + kp * 32);
    #pragma unroll
    for (int fn = 0; fn < 16; ++fn){
      long bv = *reinterpret_cast<const long*>(Br + kp * 8192 + (fn * 16 + ln) * 32 + hi * 8);
      acc0[fn] = __builtin_amdgcn_mfma_f32_16x16x32_fp8_fp8(av0, bv, acc0[fn], 0, 0, 0);
      acc1[fn] = __builtin_amdgcn_mfma_f32_16x16x32_fp8_fp8(av1, bv, acc1[fn], 0, 0, 0);
    }
  }

  float hs_l[2][4]; int wb_l[2][4];
  #pragma unroll
  for (int fm = 0; fm < 2; ++fm){
    #pragma unroll
    for (int j = 0; j < 4; ++j){
      float mv = 3.4e38f; int mi = 0;
      #pragma unroll
      for (int fn = 0; fn < 16; ++fn){
        float v = ssr[fn] - 2.f * (fm ? acc1[fn][j] : acc0[fn][j]);
        int c = fn * 16 + ln;
        if (v < mv || (v == mv && c < mi)){ mv = v; mi = c; }
      }
      #pragma unroll
      for (int m = 1; m < 16; m <<= 1){
        float ov = __shfl_xor(mv, m);
        int   oi = __shfl_xor(mi, m);
        if (ov < mv || (ov == mv && oi < mi)){ mv = ov; mi = oi; }
      }
      int r = rbase + fm * 16 + hi * 4 + j;
      if (r < M){
        float d2 = fmaxf(hh[r] + mv, 0.f);
        hs_l[fm][j] = __expf(-sqrtf(d2));
        wb_l[fm][j] = mi | (batch[r] << 8);
      } else { hs_l[fm][j] = 0.f; wb_l[fm][j] = -1; }
    }
  }

  float g0 = 0.f, g1 = 0.f, g2 = 0.f, g3 = 0.f;
  int curb = -1;
  int c0 = lane * 4;
  float cx = (float)(c0 >> 4);
  #pragma unroll
  for (int rr = 0; rr < 32; ++rr){
    const int fm = rr >> 4, sj = rr & 3, shi = (rr >> 2) & 3;
    int   wb = __shfl(wb_l[fm][sj], shi * 16);
    float hs = __shfl(hs_l[fm][sj], shi * 16);
    if (wb >= 0){
      int b = wb >> 8, win = wb & 255;
      if (b != curb){
        if (curb >= 0){
          atomicAdd(&G[curb * NU + c0    ], g0);
          atomicAdd(&G[curb * NU + c0 + 1], g1);
          atomicAdd(&G[curb * NU + c0 + 2], g2);
          atomicAdd(&G[curb * NU + c0 + 3], g3);
          g0 = g1 = g2 = g3 = 0.f;
        }
        curb = b;
      }
      float wi = (float)(win >> 4), wj = (float)(win & 15);
      float dx = cx - wi;
      float ex = hs * __expf(-dx * dx * 0.125f);
      float dy0 = (float)((c0    ) & 15) - wj;
      float dy1 = (float)((c0 + 1) & 15) - wj;
      float dy2 = (float)((c0 + 2) & 15) - wj;
      float dy3 = (float)((c0 + 3) & 15) - wj;
      g0 += ex * __expf(-dy0 * dy0 * 0.125f);
      g1 += ex * __expf(-dy1 * dy1 * 0.125f);
      g2 += ex * __expf(-dy2 * dy2 * 0.125f);
      g3 += ex * __expf(-dy3 * dy3 * 0.125f);
    }
  }
  if (curb >= 0){
    atomicAdd(&G[curb * NU + c0    ], g0);
    atomicAdd(&G[curb * NU + c0 + 1], g1);
    atomicAdd(&G[curb * NU + c0 + 2], g2);
    atomicAdd(&G[curb * NU + c0 + 3], g3);
  }
}

// Aggregation: 16-lane group owns one node (lane = 8 features, 8B loads).
// 4 nodes/wave, 8 neighbor rows in flight per group = 32 rows/wave.
// Writes fp8 slice into h8c only (GEMM A for next layer reads the same bytes).
__global__ __launch_bounds__(256) void k_agg(
    const unsigned char* __restrict__ hs8, const float* __restrict__ dinv,
    const int* __restrict__ cnt, const ushort* __restrict__ col,
    const float* __restrict__ bias,
    unsigned char* __restrict__ h8c, int cOff,
    float* __restrict__ hh, int first){
  const int lane = threadIdx.x & 63, w = threadIdx.x >> 6;
  const int g = lane >> 4, ln = lane & 15;
  const int n = (blockIdx.x * 4 + w) * 4 + g;       // 3125 blocks x 16 nodes
  if (n >= NN) return;
  const int fi = ln * 8;

  uint2 sv = *reinterpret_cast<const uint2*>(hs8 + (size_t)n * FD + fi);
  f32x2 p0 = __builtin_amdgcn_cvt_pk_f32_fp8((int)sv.x, false);
  f32x2 p1 = __builtin_amdgcn_cvt_pk_f32_fp8((int)sv.x, true );
  f32x2 p2 = __builtin_amdgcn_cvt_pk_f32_fp8((int)sv.y, false);
  f32x2 p3 = __builtin_amdgcn_cvt_pk_f32_fp8((int)sv.y, true );

  int ne = cnt[n]; if (ne > MAXDEG) ne = MAXDEG;
  const ushort* cl = col + (size_t)n * MAXDEG;
  for (int j = 0; j < ne; j += 8){
    int s[8]; float wq[8];
    #pragma unroll
    for (int q = 0; q < 8; ++q){
      int i = j + q;
      s[q] = n; wq[q] = 0.f;
      if (i < ne){ s[q] = cl[i]; wq[q] = 1.f; }
    }
    uint2 r[8];
    #pragma unroll
    for (int q = 0; q < 8; ++q)
      r[q] = *reinterpret_cast<const uint2*>(hs8 + (size_t)s[q] * FD + fi);
    #pragma unroll
    for (int q = 0; q < 8; ++q){
      f32x2 ww = {wq[q], wq[q]};
      p0 += __builtin_amdgcn_cvt_pk_f32_fp8((int)r[q].x, false) * ww;
      p1 += __builtin_amdgcn_cvt_pk_f32_fp8((int)r[q].x, true ) * ww;
      p2 += __builtin_amdgcn_cvt_pk_f32_fp8((int)r[q].y, false) * ww;
      p3 += __builtin_amdgcn_cvt_pk_f32_fp8((int)r[q].y, true ) * ww;
    }
  }
  float di = dinv[n];
  float vv[8] = {p0[0], p0[1], p1[0], p1[1], p2[0], p2[1], p3[0], p3[1]};
  float ssq = 0.f;
  #pragma unroll
  for (int k = 0; k < 8; ++k){
    float v = vv[k] * di + bias[fi + k];
    v = v > 0.f ? v : 0.01f * v;
    ssq += v * v;
    vv[k] = v;
  }
  int pa = __builtin_amdgcn_cvt_pk_fp8_f32(vv[0], vv[1], 0, false);
  pa = __builtin_amdgcn_cvt_pk_fp8_f32(vv[2], vv[3], pa, true);
  int pb = __builtin_amdgcn_cvt_pk_fp8_f32(vv[4], vv[5], 0, false);
  pb = __builtin_amdgcn_cvt_pk_fp8_f32(vv[6], vv[7], pb, true);
  uint2 pk; pk.x = (unsigned)pa; pk.y = (unsigned)pb;
  *reinterpret_cast<uint2*>(h8c + (size_t)n * LDH + cOff + fi) = pk;
  #pragma unroll
  for (int m = 1; m < 16; m <<= 1) ssq += __shfl_xor(ssq, m);
  if (ln == 0){
    if (first) hh[n] = ssq;
    else       hh[n] += ssq;
  }
}

__global__ void k_ss(const float* __restrict__ S, float* __restrict__ ss){
  int u = blockIdx.x, lane = threadIdx.x;
  const float* p = S + (size_t)u * KH + lane * 6;
  float s = 0.f;
  #pragma unroll
  for (int j = 0; j < 6; ++j){ float v = p[j]; s += v * v; }
  #pragma unroll
  for (int o = 32; o; o >>= 1) s += __shfl_down(s, o);
  if (lane == 0) ss[u] = s;
}

__global__ void k_out(const float* __restrict__ G, const float* __restrict__ lw,
                      const float* __restrict__ lb, float* __restrict__ out){
  int b = blockIdx.x, lane = threadIdx.x;
  float s = 0.f;
  #pragma unroll
  for (int j = 0; j < 4; ++j) s += G[b * NU + lane * 4 + j] * lw[lane * 4 + j];
  #pragma unroll
  for (int o = 32; o; o >>= 1) s += __shfl_down(s, o);
  if (lane == 0) out[b] = 1.f / (1.f + __expf(-(s + lb[0])));
}

extern "C" void kernel_launch(void* const* d_in, const int* in_sizes, int n_in,
                              void* d_out, int out_size, void* d_ws, size_t ws_size,
                              hipStream_t stream){
  const float* x   = (const float*)d_in[0];
  const int*   ei  = (const int*)d_in[1];
  const int*   bat = (const int*)d_in[2];
  const float* W1  = (const float*)d_in[3];
  const float* b1  = (const float*)d_in[4];
  const float* W2  = (const float*)d_in[5];
  const float* b2  = (const float*)d_in[6];
  const float* W3  = (const float*)d_in[7];
  const float* b3  = (const float*)d_in[8];
  const float* S   = (const float*)d_in[9];
  const float* lw  = (const float*)d_in[10];
  const float* lb  = (const float*)d_in[11];
  float* out = (float*)d_out;
  char* w = (char*)d_ws;

  int*      pos  = (int*)     (w + OFF_POS);
  float*    G    = (float*)   (w + OFF_G);
  int*      cnt  = (int*)     (w + OFF_CNT);
  unsigned* be   = (unsigned*)(w + OFF_BE);
  ushort*   col  = (ushort*)  (w + OFF_COL);
  float*    dinv = (float*)   (w + OFF_DINV);
  unsigned char* x8  = (unsigned char*)(w + OFF_X8);
  unsigned char* h8  = (unsigned char*)(w + OFF_H8);
  unsigned char* h8c = (unsigned char*)(w + OFF_H8C);
  float*    hh   = (float*)   (w + OFF_HH);
  unsigned char* w8r = (unsigned char*)(w + OFF_W8R);
  unsigned char* sbr = (unsigned char*)(w + OFF_SBR);
  float*    ss   = (float*)   (w + OFF_SS);

  hipMemsetAsync(w, 0, 66048, stream);                      // pos + G

  k_prep<<<6538, 256, 0, stream>>>(x, (unsigned*)x8, S, (unsigned*)sbr,
                                   W1, W2, W3, w8r);
  k_bin<<<196, 256, 0, stream>>>(ei, pos, be);
  k_build<<<NB, 256, 0, stream>>>(pos, be, cnt, col, dinv);

  dim3 blk(256);
  // layer 1
  k_gemm8<<<391, blk, 0, stream>>>(x8, FD, w8r, h8, dinv);
  k_agg<<<3125, 256, 0, stream>>>(h8, dinv, cnt, col, b1, h8c, 0, hh, 1);
  // layer 2 (A = h8c[:,0:128))
  k_gemm8<<<391, blk, 0, stream>>>(h8c, LDH, w8r + 16384, h8, dinv);
  k_agg<<<3125, 256, 0, stream>>>(h8, dinv, cnt, col, b2, h8c, 128, hh, 0);
  // layer 3 (A = h8c[:,128:256))
  k_gemm8<<<391, blk, 0, stream>>>(h8c + 128, LDH, w8r + 32768, h8, dinv);
  k_agg<<<3125, 256, 0, stream>>>(h8, dinv, cnt, col, b3, h8c, 256, hh, 0);

  k_ss<<<256, 64, 0, stream>>>(S, ss);
  // wave-autonomous fused SOM
  k_gsom<<<391, blk, 0, stream>>>(h8c, sbr, ss, hh, bat, G, NN);
  k_out<<<64, 64, 0, stream>>>(G, lw, lb, out);
}

// Round 13
// 169.695 us; speedup vs baseline: 1.3591x; 1.0163x over previous
//
#include <hip/hip_runtime.h>

#define NN 50000
#define NE 800000
#define FD 128
#define KH 384
#define NU 256
#define NG 64
#define MAXDEG 64
#define NB 98          // dst buckets of 512 nodes
#define BCAP 10240     // per-bucket capacity
#define EPB 4096       // edges per k_bin block
#define LDH 400        // padded fp8 row (400 B) for H-concat

typedef __attribute__((__ext_vector_type__(4))) float f32x4;
typedef __attribute__((__ext_vector_type__(2))) float f32x2;

// ---- ws layout (bytes, 16B-aligned) ----
#define OFF_POS   0u           // NB int (+pad)         512     [memset]
#define OFF_G     512u         // 64*256 f32            65536   [memset]
#define OFF_CNT   66048u       // 50048 int             200192
#define OFF_BE    266240u      // NB*BCAP u32           4014080
#define OFF_COL   4280320u     // 50048*64 u16          6406144
#define OFF_DINV  10686464u    // 50048 f32             200192
#define OFF_X8    10886656u    // 50048*128 fp8         6406144
#define OFF_H8    17292800u    // 50048*128 fp8         6406144
#define OFF_H8C   23698944u    // 50048*400B fp8pad     20019200
#define OFF_HH    43718144u    // 50048 f32             200192
#define OFF_W8R   43918336u    // 3*[4][128][32] fp8    49152
#define OFF_SBR   43967488u    // [12][256][32] fp8     98304
#define OFF_SS    44065792u    // 256 f32               1024   -> total 44066816

// Fused prep: x->fp8; S->fp8 frag-contiguous; W1..3->fp8 frag-contiguous; ss.
__global__ __launch_bounds__(256) void k_prep(
    const float* __restrict__ x, unsigned* __restrict__ x8,
    const float* __restrict__ S, unsigned* __restrict__ sbr,
    const float* __restrict__ W1, const float* __restrict__ W2,
    const float* __restrict__ W3, unsigned char* __restrict__ w8r,
    float* __restrict__ ss){
  int tid = blockIdx.x * 256 + threadIdx.x;
  if (tid < 1600000){                    // x: 50000*128/4 quads
    float4 v = reinterpret_cast<const float4*>(x)[tid];
    int p = __builtin_amdgcn_cvt_pk_fp8_f32(v.x, v.y, 0, false);
    p = __builtin_amdgcn_cvt_pk_fp8_f32(v.z, v.w, p, true);
    x8[tid] = (unsigned)p;
  } else if (tid < 1624576){             // S: 256*384/4 quads
    int t = tid - 1600000;
    int c = t / 96, k0 = (t % 96) * 4;
    float4 v = *reinterpret_cast<const float4*>(S + (size_t)c * KH + k0);
    int p = __builtin_amdgcn_cvt_pk_fp8_f32(v.x, v.y, 0, false);
    p = __builtin_amdgcn_cvt_pk_fp8_f32(v.z, v.w, p, true);
    sbr[((k0 >> 5) * 8192 + c * 32 + (k0 & 31)) >> 2] = (unsigned)p;
  } else if (tid < 1673728){             // W: 3*128*128 elements
    int t = tid - 1624576;
    int wi = t >> 14, e = t & 16383;
    int k = e >> 7, n = e & 127;
    const float* W = (wi == 0) ? W1 : (wi == 1) ? W2 : W3;
    float v = W[k * FD + n];
    int p = __builtin_amdgcn_cvt_pk_fp8_f32(v, v, 0, false);
    w8r[wi * 16384 + (k >> 5) * 4096 + n * 32 + (k & 31)] = (unsigned char)p;
  } else if (tid < 1690112){             // ss: 256 units x 64 lanes
    int t = tid - 1673728;               // 1673728 % 64 == 0 -> wave-aligned
    int u = t >> 6, lane = t & 63;
    const float* p = S + (size_t)u * KH + lane * 6;
    float s = 0.f;
    #pragma unroll
    for (int j = 0; j < 6; ++j){ float v = p[j]; s += v * v; }
    #pragma unroll
    for (int o = 32; o; o >>= 1) s += __shfl_down(s, o);
    if (lane == 0) ss[u] = s;
  }
}

// phase A: bin edges by dst>>9, dense bucket appends
__global__ __launch_bounds__(256) void k_bin(const int* __restrict__ ei,
                                             int* __restrict__ bucketPos,
                                             unsigned* __restrict__ be){
  __shared__ int hist[NB], base[NB], off[NB];
  int t = threadIdx.x;
  for (int i = t; i < NB; i += 256) hist[i] = 0;
  __syncthreads();
  int e0 = blockIdx.x * EPB;
  int e1 = min(e0 + EPB, NE);
  for (int e = e0 + t; e < e1; e += 256)
    atomicAdd(&hist[ei[NE + e] >> 9], 1);
  __syncthreads();
  for (int i = t; i < NB; i += 256){
    base[i] = atomicAdd(&bucketPos[i], hist[i]);
    off[i] = 0;
  }
  __syncthreads();
  for (int e = e0 + t; e < e1; e += 256){
    int d = ei[NE + e], s = ei[e];
    int b = d >> 9;
    int p = base[b] + atomicAdd(&off[b], 1);
    if (p < BCAP) be[(size_t)b * BCAP + p] = ((unsigned)(d & 511) << 16) | (unsigned)s;
  }
}

// phase B: one block per bucket; LDS degree counters; L2-local col scatter.
__global__ __launch_bounds__(256) void k_build(const int* __restrict__ bucketPos,
                                               const unsigned* __restrict__ be,
                                               int* __restrict__ cnt,
                                               ushort* __restrict__ col,
                                               float* __restrict__ dinv){
  __shared__ int lcnt[512];
  int t = threadIdx.x, b = blockIdx.x;
  for (int i = t; i < 512; i += 256) lcnt[i] = 0;
  __syncthreads();
  int nE = min(bucketPos[b], BCAP);
  const unsigned* bb = be + (size_t)b * BCAP;
  for (int i = t; i < nE; i += 256){
    unsigned u = bb[i];
    int dl = u >> 16, s = u & 0xffffu;
    int pos = atomicAdd(&lcnt[dl], 1);
    if (pos < MAXDEG) col[(size_t)(b * 512 + dl) * MAXDEG + pos] = (ushort)s;
  }
  __syncthreads();
  for (int i = t; i < 512; i += 256){
    int n = b * 512 + i;
    if (n < NN){
      cnt[n] = lcnt[i];
      dinv[n] = rsqrtf((float)(lcnt[i] + 1));
    }
  }
}

// Wave-autonomous fp8 layer GEMM: wave owns 32 rows x 128 cols, K=128.
__global__ __launch_bounds__(256, 2) void k_gemm8(
    const unsigned char* __restrict__ A8, int strideA,
    const unsigned char* __restrict__ W8,
    unsigned char* __restrict__ C8,
    const float* __restrict__ dinv){
  const int lane = threadIdx.x & 63, w = threadIdx.x >> 6;
  const int ln = lane & 15, hi = lane >> 4;
  const int rbase = (blockIdx.x * 4 + w) * 32;

  f32x4 acc0[8], acc1[8];
  #pragma unroll
  for (int i = 0; i < 8; ++i){
    acc0[i] = (f32x4){0.f,0.f,0.f,0.f};
    acc1[i] = (f32x4){0.f,0.f,0.f,0.f};
  }
  const unsigned char* Ar0 = A8 + (size_t)(rbase + ln) * strideA + hi * 8;
  const unsigned char* Ar1 = Ar0 + (size_t)16 * strideA;
  #pragma unroll
  for (int kp = 0; kp < 4; ++kp){
    long av0 = *reinterpret_cast<const long*>(Ar0 + kp * 32);
    long av1 = *reinterpret_cast<const long*>(Ar1 + kp * 32);
    #pragma unroll
    for (int fn = 0; fn < 8; ++fn){
      long bv = *reinterpret_cast<const long*>(W8 + kp * 4096 + (fn * 16 + ln) * 32 + hi * 8);
      acc0[fn] = __builtin_amdgcn_mfma_f32_16x16x32_fp8_fp8(av0, bv, acc0[fn], 0, 0, 0);
      acc1[fn] = __builtin_amdgcn_mfma_f32_16x16x32_fp8_fp8(av1, bv, acc1[fn], 0, 0, 0);
    }
  }
  #pragma unroll
  for (int fm = 0; fm < 2; ++fm){
    #pragma unroll
    for (int j = 0; j < 4; ++j){
      int r = rbase + fm * 16 + hi * 4 + j;
      float di = dinv[r];
      #pragma unroll
      for (int fn = 0; fn < 8; ++fn){
        float v = (fm ? acc1[fn][j] : acc0[fn][j]) * di;
        int p = __builtin_amdgcn_cvt_pk_fp8_f32(v, v, 0, false);
        C8[(size_t)r * FD + fn * 16 + ln] = (unsigned char)p;
      }
    }
  }
}

// Wave-autonomous fused SOM: each wave owns 32 rows x 256 units. No LDS/barriers.
__global__ __launch_bounds__(256, 2) void k_gsom(
    const unsigned char* __restrict__ A8,   // h8c padded rows of LDH
    const unsigned char* __restrict__ Br,   // Sb8r [12][256][32]
    const float* __restrict__ ss, const float* __restrict__ hh,
    const int* __restrict__ batch, float* __restrict__ G, int M){
  const int lane = threadIdx.x & 63, w = threadIdx.x >> 6;
  const int ln = lane & 15, hi = lane >> 4;
  const int gw = blockIdx.x * 4 + w;
  const int rbase = gw * 32;

  float ssr[16];
  #pragma unroll
  for (int fn = 0; fn < 16; ++fn) ssr[fn] = ss[fn * 16 + ln];

  f32x4 acc0[16], acc1[16];
  #pragma unroll
  for (int i = 0; i < 16; ++i){
    acc0[i] = (f32x4){0.f,0.f,0.f,0.f};
    acc1[i] = (f32x4){0.f,0.f,0.f,0.f};
  }

  const unsigned char* Arow0 = A8 + (size_t)(rbase + ln) * LDH + hi * 8;
  const unsigned char* Arow1 = Arow0 + 16 * LDH;
  #pragma unroll
  for (int kp = 0; kp < 12; ++kp){
    long av0 = *reinterpret_cast<const long*>(Arow0 + kp * 32);
    long av1 = *reinterpret_cast<const long*>(Arow1 + kp * 32);
    #pragma unroll
    for (int fn = 0; fn < 16; ++fn){
      long bv = *reinterpret_cast<const long*>(Br + kp * 8192 + (fn * 16 + ln) * 32 + hi * 8);
      acc0[fn] = __builtin_amdgcn_mfma_f32_16x16x32_fp8_fp8(av0, bv, acc0[fn], 0, 0, 0);
      acc1[fn] = __builtin_amdgcn_mfma_f32_16x16x32_fp8_fp8(av1, bv, acc1[fn], 0, 0, 0);
    }
  }

  float hs_l[2][4]; int wb_l[2][4];
  #pragma unroll
  for (int fm = 0; fm < 2; ++fm){
    #pragma unroll
    for (int j = 0; j < 4; ++j){
      float mv = 3.4e38f; int mi = 0;
      #pragma unroll
      for (int fn = 0; fn < 16; ++fn){
        float v = ssr[fn] - 2.f * (fm ? acc1[fn][j] : acc0[fn][j]);
        int c = fn * 16 + ln;
        if (v < mv || (v == mv && c < mi)){ mv = v; mi = c; }
      }
      #pragma unroll
      for (int m = 1; m < 16; m <<= 1){
        float ov = __shfl_xor(mv, m);
        int   oi = __shfl_xor(mi, m);
        if (ov < mv || (ov == mv && oi < mi)){ mv = ov; mi = oi; }
      }
      int r = rbase + fm * 16 + hi * 4 + j;
      if (r < M){
        float d2 = fmaxf(hh[r] + mv, 0.f);
        hs_l[fm][j] = __expf(-sqrtf(d2));
        wb_l[fm][j] = mi | (batch[r] << 8);
      } else { hs_l[fm][j] = 0.f; wb_l[fm][j] = -1; }
    }
  }

  float g0 = 0.f, g1 = 0.f, g2 = 0.f, g3 = 0.f;
  int curb = -1;
  int c0 = lane * 4;
  float cx = (float)(c0 >> 4);
  #pragma unroll
  for (int rr = 0; rr < 32; ++rr){
    const int fm = rr >> 4, sj = rr & 3, shi = (rr >> 2) & 3;
    int   wb = __shfl(wb_l[fm][sj], shi * 16);
    float hs = __shfl(hs_l[fm][sj], shi * 16);
    if (wb >= 0){
      int b = wb >> 8, win = wb & 255;
      if (b != curb){
        if (curb >= 0){
          atomicAdd(&G[curb * NU + c0    ], g0);
          atomicAdd(&G[curb * NU + c0 + 1], g1);
          atomicAdd(&G[curb * NU + c0 + 2], g2);
          atomicAdd(&G[curb * NU + c0 + 3], g3);
          g0 = g1 = g2 = g3 = 0.f;
        }
        curb = b;
      }
      float wi = (float)(win >> 4), wj = (float)(win & 15);
      float dx = cx - wi;
      float ex = hs * __expf(-dx * dx * 0.125f);
      float dy0 = (float)((c0    ) & 15) - wj;
      float dy1 = (float)((c0 + 1) & 15) - wj;
      float dy2 = (float)((c0 + 2) & 15) - wj;
      float dy3 = (float)((c0 + 3) & 15) - wj;
      g0 += ex * __expf(-dy0 * dy0 * 0.125f);
      g1 += ex * __expf(-dy1 * dy1 * 0.125f);
      g2 += ex * __expf(-dy2 * dy2 * 0.125f);
      g3 += ex * __expf(-dy3 * dy3 * 0.125f);
    }
  }
  if (curb >= 0){
    atomicAdd(&G[curb * NU + c0    ], g0);
    atomicAdd(&G[curb * NU + c0 + 1], g1);
    atomicAdd(&G[curb * NU + c0 + 2], g2);
    atomicAdd(&G[curb * NU + c0 + 3], g3);
  }
}

// Aggregation: 16-lane group owns one node (lane = 8 features, 8B loads).
// Whole 64-entry col list read in ONE ushort4/lane; indices via shfl.
// 16 neighbor rows in flight per group = 64 rows (8KB) per wave.
__global__ __launch_bounds__(256) void k_agg(
    const unsigned char* __restrict__ hs8, const float* __restrict__ dinv,
    const int* __restrict__ cnt, const ushort* __restrict__ col,
    const float* __restrict__ bias,
    unsigned char* __restrict__ h8c, int cOff,
    float* __restrict__ hh, int first){
  const int lane = threadIdx.x & 63, w = threadIdx.x >> 6;
  const int g = lane >> 4, ln = lane & 15;
  const int n = (blockIdx.x * 4 + w) * 4 + g;       // 3125 blocks x 16 nodes
  if (n >= NN) return;
  const int fi = ln * 8;

  // self row + whole col list (one 8B load per lane covers 64 entries/group)
  uint2 sv = *reinterpret_cast<const uint2*>(hs8 + (size_t)n * FD + fi);
  ushort4 colv = *reinterpret_cast<const ushort4*>(col + (size_t)n * MAXDEG + ln * 4);
  unsigned u0 = (unsigned)colv.x | ((unsigned)colv.y << 16);
  unsigned u1 = (unsigned)colv.z | ((unsigned)colv.w << 16);

  f32x2 p0 = __builtin_amdgcn_cvt_pk_f32_fp8((int)sv.x, false);
  f32x2 p1 = __builtin_amdgcn_cvt_pk_f32_fp8((int)sv.x, true );
  f32x2 p2 = __builtin_amdgcn_cvt_pk_f32_fp8((int)sv.y, false);
  f32x2 p3 = __builtin_amdgcn_cvt_pk_f32_fp8((int)sv.y, true );

  int ne = cnt[n]; if (ne > MAXDEG) ne = MAXDEG;
  #pragma unroll
  for (int b = 0; b < 4; ++b){
    const int j0 = b * 16;
    if (j0 < ne){
      uint2 r[16]; float wq[16];
      #pragma unroll
      for (int q = 0; q < 16; ++q){
        int i = j0 + q;
        int sl = (g << 4) + (i >> 2);              // lane holding entry i
        unsigned uu = __shfl((q & 2) ? u1 : u0, sl);
        unsigned sidx = (q & 1) ? (uu >> 16) : (uu & 0xffffu);
        bool ok = (i < ne);
        wq[q] = ok ? 1.f : 0.f;
        unsigned srow = ok ? sidx : (unsigned)n;
        r[q] = *reinterpret_cast<const uint2*>(hs8 + (size_t)srow * FD + fi);
      }
      #pragma unroll
      for (int q = 0; q < 16; ++q){
        f32x2 ww = {wq[q], wq[q]};
        p0 += __builtin_amdgcn_cvt_pk_f32_fp8((int)r[q].x, false) * ww;
        p1 += __builtin_amdgcn_cvt_pk_f32_fp8((int)r[q].x, true ) * ww;
        p2 += __builtin_amdgcn_cvt_pk_f32_fp8((int)r[q].y, false) * ww;
        p3 += __builtin_amdgcn_cvt_pk_f32_fp8((int)r[q].y, true ) * ww;
      }
    }
  }
  float di = dinv[n];
  float vv[8] = {p0[0], p0[1], p1[0], p1[1], p2[0], p2[1], p3[0], p3[1]};
  float ssq = 0.f;
  #pragma unroll
  for (int k = 0; k < 8; ++k){
    float v = vv[k] * di + bias[fi + k];
    v = v > 0.f ? v : 0.01f * v;
    ssq += v * v;
    vv[k] = v;
  }
  int pa = __builtin_amdgcn_cvt_pk_fp8_f32(vv[0], vv[1], 0, false);
  pa = __builtin_amdgcn_cvt_pk_fp8_f32(vv[2], vv[3], pa, true);
  int pb = __builtin_amdgcn_cvt_pk_fp8_f32(vv[4], vv[5], 0, false);
  pb = __builtin_amdgcn_cvt_pk_fp8_f32(vv[6], vv[7], pb, true);
  uint2 pk; pk.x = (unsigned)pa; pk.y = (unsigned)pb;
  *reinterpret_cast<uint2*>(h8c + (size_t)n * LDH + cOff + fi) = pk;
  #pragma unroll
  for (int m = 1; m < 16; m <<= 1) ssq += __shfl_xor(ssq, m);
  if (ln == 0){
    if (first) hh[n] = ssq;
    else       hh[n] += ssq;
  }
}

__global__ void k_out(const float* __restrict__ G, const float* __restrict__ lw,
                      const float* __restrict__ lb, float* __restrict__ out){
  int b = blockIdx.x, lane = threadIdx.x;
  float s = 0.f;
  #pragma unroll
  for (int j = 0; j < 4; ++j) s += G[b * NU + lane * 4 + j] * lw[lane * 4 + j];
  #pragma unroll
  for (int o = 32; o; o >>= 1) s += __shfl_down(s, o);
  if (lane == 0) out[b] = 1.f / (1.f + __expf(-(s + lb[0])));
}

extern "C" void kernel_launch(void* const* d_in, const int* in_sizes, int n_in,
                              void* d_out, int out_size, void* d_ws, size_t ws_size,
                              hipStream_t stream){
  const float* x   = (const float*)d_in[0];
  const int*   ei  = (const int*)d_in[1];
  const int*   bat = (const int*)d_in[2];
  const float* W1  = (const float*)d_in[3];
  const float* b1  = (const float*)d_in[4];
  const float* W2  = (const float*)d_in[5];
  const float* b2  = (const float*)d_in[6];
  const float* W3  = (const float*)d_in[7];
  const float* b3  = (const float*)d_in[8];
  const float* S   = (const float*)d_in[9];
  const float* lw  = (const float*)d_in[10];
  const float* lb  = (const float*)d_in[11];
  float* out = (float*)d_out;
  char* w = (char*)d_ws;

  int*      pos  = (int*)     (w + OFF_POS);
  float*    G    = (float*)   (w + OFF_G);
  int*      cnt  = (int*)     (w + OFF_CNT);
  unsigned* be   = (unsigned*)(w + OFF_BE);
  ushort*   col  = (ushort*)  (w + OFF_COL);
  float*    dinv = (float*)   (w + OFF_DINV);
  unsigned char* x8  = (unsigned char*)(w + OFF_X8);
  unsigned char* h8  = (unsigned char*)(w + OFF_H8);
  unsigned char* h8c = (unsigned char*)(w + OFF_H8C);
  float*    hh   = (float*)   (w + OFF_HH);
  unsigned char* w8r = (unsigned char*)(w + OFF_W8R);
  unsigned char* sbr = (unsigned char*)(w + OFF_SBR);
  float*    ss   = (float*)   (w + OFF_SS);

  hipMemsetAsync(w, 0, 66048, stream);                      // pos + G

  k_prep<<<6602, 256, 0, stream>>>(x, (unsigned*)x8, S, (unsigned*)sbr,
                                   W1, W2, W3, w8r, ss);
  k_bin<<<196, 256, 0, stream>>>(ei, pos, be);
  k_build<<<NB, 256, 0, stream>>>(pos, be, cnt, col, dinv);

  dim3 blk(256);
  // layer 1
  k_gemm8<<<391, blk, 0, stream>>>(x8, FD, w8r, h8, dinv);
  k_agg<<<3125, 256, 0, stream>>>(h8, dinv, cnt, col, b1, h8c, 0, hh, 1);
  // layer 2 (A = h8c[:,0:128))
  k_gemm8<<<391, blk, 0, stream>>>(h8c, LDH, w8r + 16384, h8, dinv);
  k_agg<<<3125, 256, 0, stream>>>(h8, dinv, cnt, col, b2, h8c, 128, hh, 0);
  // layer 3 (A = h8c[:,128:256))
  k_gemm8<<<391, blk, 0, stream>>>(h8c + 128, LDH, w8r + 32768, h8, dinv);
  k_agg<<<3125, 256, 0, stream>>>(h8, dinv, cnt, col, b3, h8c, 256, hh, 0);

  // wave-autonomous fused SOM
  k_gsom<<<391, blk, 0, stream>>>(h8c, sbr, ss, hh, bat, G, NN);
  k_out<<<64, 64, 0, stream>>>(G, lw, lb, out);
}

// Round 14
// 156.002 us; speedup vs baseline: 1.4784x; 1.0878x over previous
//
#include <hip/hip_runtime.h>

#define NN 50000
#define NE 800000
#define FD 128
#define KH 384
#define NU 256
#define NG 64
#define MAXDEG 64
#define NB 98          // dst buckets of 512 nodes
#define BCAP 10240     // per-bucket capacity
#define EPB 4096       // edges per k_bin block
#define LDH 400        // padded fp8 row (400 B) for H-concat

typedef __attribute__((__ext_vector_type__(4))) float f32x4;
typedef __attribute__((__ext_vector_type__(2))) float f32x2;

// ---- ws layout (bytes, 16B-aligned) ----
#define OFF_POS   0u           // NB int (+pad)         512     [memset]
#define OFF_G     512u         // 64*256 f32            65536   [memset]
#define OFF_CNT   66048u       // 50048 int             200192
#define OFF_BE    266240u      // NB*BCAP u32           4014080
#define OFF_COL   4280320u     // 50048*64 u16          6406144
#define OFF_DINV  10686464u    // 50048 f32             200192
#define OFF_X8    10886656u    // 50048*128 fp8         6406144
#define OFF_H4    17292800u    // 50048*64 int4-packed  3203072
#define OFF_H8C   23698944u    // 50048*400B fp8pad     20019200
#define OFF_HH    43718144u    // 50048 f32             200192
#define OFF_W8R   43918336u    // 3*[4][128][32] fp8    49152
#define OFF_SBR   43967488u    // [12][256][32] fp8     98304
#define OFF_SS    44065792u    // 256 f32               1024   -> total 44066816

// Fused prep+bin. Blocks 0..195: edge binning. Blocks 196+: conversions.
__global__ __launch_bounds__(256) void k_pb(
    const int* __restrict__ ei, int* __restrict__ bucketPos, unsigned* __restrict__ be,
    const float* __restrict__ x, unsigned* __restrict__ x8,
    const float* __restrict__ S, unsigned* __restrict__ sbr,
    const float* __restrict__ W1, const float* __restrict__ W2,
    const float* __restrict__ W3, unsigned char* __restrict__ w8r,
    float* __restrict__ ss){
  if (blockIdx.x < 196){
    __shared__ int hist[NB], base[NB], off[NB];
    int t = threadIdx.x;
    for (int i = t; i < NB; i += 256) hist[i] = 0;
    __syncthreads();
    int e0 = blockIdx.x * EPB;
    int e1 = min(e0 + EPB, NE);
    for (int e = e0 + t; e < e1; e += 256)
      atomicAdd(&hist[ei[NE + e] >> 9], 1);
    __syncthreads();
    for (int i = t; i < NB; i += 256){
      base[i] = atomicAdd(&bucketPos[i], hist[i]);
      off[i] = 0;
    }
    __syncthreads();
    for (int e = e0 + t; e < e1; e += 256){
      int d = ei[NE + e], s = ei[e];
      int b = d >> 9;
      int p = base[b] + atomicAdd(&off[b], 1);
      if (p < BCAP) be[(size_t)b * BCAP + p] = ((unsigned)(d & 511) << 16) | (unsigned)s;
    }
    return;
  }
  int tid = (blockIdx.x - 196) * 256 + threadIdx.x;
  if (tid < 1600000){                    // x: 50000*128/4 quads
    float4 v = reinterpret_cast<const float4*>(x)[tid];
    int p = __builtin_amdgcn_cvt_pk_fp8_f32(v.x, v.y, 0, false);
    p = __builtin_amdgcn_cvt_pk_fp8_f32(v.z, v.w, p, true);
    x8[tid] = (unsigned)p;
  } else if (tid < 1624576){             // S: 256*384/4 quads
    int t = tid - 1600000;
    int c = t / 96, k0 = (t % 96) * 4;
    float4 v = *reinterpret_cast<const float4*>(S + (size_t)c * KH + k0);
    int p = __builtin_amdgcn_cvt_pk_fp8_f32(v.x, v.y, 0, false);
    p = __builtin_amdgcn_cvt_pk_fp8_f32(v.z, v.w, p, true);
    sbr[((k0 >> 5) * 8192 + c * 32 + (k0 & 31)) >> 2] = (unsigned)p;
  } else if (tid < 1673728){             // W: 3*128*128 elements
    int t = tid - 1624576;
    int wi = t >> 14, e = t & 16383;
    int k = e >> 7, n = e & 127;
    const float* W = (wi == 0) ? W1 : (wi == 1) ? W2 : W3;
    float v = W[k * FD + n];
    int p = __builtin_amdgcn_cvt_pk_fp8_f32(v, v, 0, false);
    w8r[wi * 16384 + (k >> 5) * 4096 + n * 32 + (k & 31)] = (unsigned char)p;
  } else if (tid < 1690112){             // ss: 256 units x 64 lanes
    int t = tid - 1673728;
    int u = t >> 6, lane = t & 63;
    const float* p = S + (size_t)u * KH + lane * 6;
    float s = 0.f;
    #pragma unroll
    for (int j = 0; j < 6; ++j){ float v = p[j]; s += v * v; }
    #pragma unroll
    for (int o = 32; o; o >>= 1) s += __shfl_down(s, o);
    if (lane == 0) ss[u] = s;
  }
}

// phase B: one block per bucket; LDS degree counters; L2-local col scatter.
__global__ __launch_bounds__(256) void k_build(const int* __restrict__ bucketPos,
                                               const unsigned* __restrict__ be,
                                               int* __restrict__ cnt,
                                               ushort* __restrict__ col,
                                               float* __restrict__ dinv){
  __shared__ int lcnt[512];
  int t = threadIdx.x, b = blockIdx.x;
  for (int i = t; i < 512; i += 256) lcnt[i] = 0;
  __syncthreads();
  int nE = min(bucketPos[b], BCAP);
  const unsigned* bb = be + (size_t)b * BCAP;
  for (int i = t; i < nE; i += 256){
    unsigned u = bb[i];
    int dl = u >> 16, s = u & 0xffffu;
    int pos = atomicAdd(&lcnt[dl], 1);
    if (pos < MAXDEG) col[(size_t)(b * 512 + dl) * MAXDEG + pos] = (ushort)s;
  }
  __syncthreads();
  for (int i = t; i < 512; i += 256){
    int n = b * 512 + i;
    if (n < NN){
      cnt[n] = lcnt[i];
      dinv[n] = rsqrtf((float)(lcnt[i] + 1));
    }
  }
}

// Wave-autonomous fp8 layer GEMM: wave owns 32 rows x 128 cols, K=128.
// Epilogue: v = acc*dinv[r]; pack int4 excess-8, byte f holds feats (f, f+64).
__global__ __launch_bounds__(256, 2) void k_gemm8(
    const unsigned char* __restrict__ A8, int strideA,
    const unsigned char* __restrict__ W8,
    unsigned char* __restrict__ h4,
    const float* __restrict__ dinv){
  const int lane = threadIdx.x & 63, w = threadIdx.x >> 6;
  const int ln = lane & 15, hi = lane >> 4;
  const int rbase = (blockIdx.x * 4 + w) * 32;

  f32x4 acc0[8], acc1[8];
  #pragma unroll
  for (int i = 0; i < 8; ++i){
    acc0[i] = (f32x4){0.f,0.f,0.f,0.f};
    acc1[i] = (f32x4){0.f,0.f,0.f,0.f};
  }
  const unsigned char* Ar0 = A8 + (size_t)(rbase + ln) * strideA + hi * 8;
  const unsigned char* Ar1 = Ar0 + (size_t)16 * strideA;
  #pragma unroll
  for (int kp = 0; kp < 4; ++kp){
    long av0 = *reinterpret_cast<const long*>(Ar0 + kp * 32);
    long av1 = *reinterpret_cast<const long*>(Ar1 + kp * 32);
    #pragma unroll
    for (int fn = 0; fn < 8; ++fn){
      long bv = *reinterpret_cast<const long*>(W8 + kp * 4096 + (fn * 16 + ln) * 32 + hi * 8);
      acc0[fn] = __builtin_amdgcn_mfma_f32_16x16x32_fp8_fp8(av0, bv, acc0[fn], 0, 0, 0);
      acc1[fn] = __builtin_amdgcn_mfma_f32_16x16x32_fp8_fp8(av1, bv, acc1[fn], 0, 0, 0);
    }
  }
  #pragma unroll
  for (int fm = 0; fm < 2; ++fm){
    #pragma unroll
    for (int j = 0; j < 4; ++j){
      int r = rbase + fm * 16 + hi * 4 + j;
      float di = dinv[r];
      float v[8];
      #pragma unroll
      for (int fn = 0; fn < 8; ++fn) v[fn] = (fm ? acc1[fn][j] : acc0[fn][j]) * di;
      #pragma unroll
      for (int fn = 0; fn < 4; ++fn){
        int lo = (int)(fminf(fmaxf(rintf(v[fn]     * 8.f) + 8.f, 0.f), 15.f));
        int hh = (int)(fminf(fmaxf(rintf(v[fn + 4] * 8.f) + 8.f, 0.f), 15.f));
        h4[(size_t)r * 64 + fn * 16 + ln] = (unsigned char)(lo | (hh << 4));
      }
    }
  }
}

// Wave-autonomous fused SOM: each wave owns 32 rows x 256 units. No LDS/barriers.
__global__ __launch_bounds__(256, 2) void k_gsom(
    const unsigned char* __restrict__ A8,   // h8c padded rows of LDH
    const unsigned char* __restrict__ Br,   // Sb8r [12][256][32]
    const float* __restrict__ ss, const float* __restrict__ hh,
    const int* __restrict__ batch, float* __restrict__ G, int M){
  const int lane = threadIdx.x & 63, w = threadIdx.x >> 6;
  const int ln = lane & 15, hi = lane >> 4;
  const int gw = blockIdx.x * 4 + w;
  const int rbase = gw * 32;

  float ssr[16];
  #pragma unroll
  for (int fn = 0; fn < 16; ++fn) ssr[fn] = ss[fn * 16 + ln];

  f32x4 acc0[16], acc1[16];
  #pragma unroll
  for (int i = 0; i < 16; ++i){
    acc0[i] = (f32x4){0.f,0.f,0.f,0.f};
    acc1[i] = (f32x4){0.f,0.f,0.f,0.f};
  }

  const unsigned char* Arow0 = A8 + (size_t)(rbase + ln) * LDH + hi * 8;
  const unsigned char* Arow1 = Arow0 + 16 * LDH;
  #pragma unroll
  for (int kp = 0; kp < 12; ++kp){
    long av0 = *reinterpret_cast<const long*>(Arow0 + kp * 32);
    long av1 = *reinterpret_cast<const long*>(Arow1 + kp * 32);
    #pragma unroll
    for (int fn = 0; fn < 16; ++fn){
      long bv = *reinterpret_cast<const long*>(Br + kp * 8192 + (fn * 16 + ln) * 32 + hi * 8);
      acc0[fn] = __builtin_amdgcn_mfma_f32_16x16x32_fp8_fp8(av0, bv, acc0[fn], 0, 0, 0);
      acc1[fn] = __builtin_amdgcn_mfma_f32_16x16x32_fp8_fp8(av1, bv, acc1[fn], 0, 0, 0);
    }
  }

  float hs_l[2][4]; int wb_l[2][4];
  #pragma unroll
  for (int fm = 0; fm < 2; ++fm){
    #pragma unroll
    for (int j = 0; j < 4; ++j){
      float mv = 3.4e38f; int mi = 0;
      #pragma unroll
      for (int fn = 0; fn < 16; ++fn){
        float v = ssr[fn] - 2.f * (fm ? acc1[fn][j] : acc0[fn][j]);
        int c = fn * 16 + ln;
        if (v < mv || (v == mv && c < mi)){ mv = v; mi = c; }
      }
      #pragma unroll
      for (int m = 1; m < 16; m <<= 1){
        float ov = __shfl_xor(mv, m);
        int   oi = __shfl_xor(mi, m);
        if (ov < mv || (ov == mv && oi < mi)){ mv = ov; mi = oi; }
      }
      int r = rbase + fm * 16 + hi * 4 + j;
      if (r < M){
        float d2 = fmaxf(hh[r] + mv, 0.f);
        hs_l[fm][j] = __expf(-sqrtf(d2));
        wb_l[fm][j] = mi | (batch[r] << 8);
      } else { hs_l[fm][j] = 0.f; wb_l[fm][j] = -1; }
    }
  }

  float g0 = 0.f, g1 = 0.f, g2 = 0.f, g3 = 0.f;
  int curb = -1;
  int c0 = lane * 4;
  float cx = (float)(c0 >> 4);
  #pragma unroll
  for (int rr = 0; rr < 32; ++rr){
    const int fm = rr >> 4, sj = rr & 3, shi = (rr >> 2) & 3;
    int   wb = __shfl(wb_l[fm][sj], shi * 16);
    float hs = __shfl(hs_l[fm][sj], shi * 16);
    if (wb >= 0){
      int b = wb >> 8, win = wb & 255;
      if (b != curb){
        if (curb >= 0){
          atomicAdd(&G[curb * NU + c0    ], g0);
          atomicAdd(&G[curb * NU + c0 + 1], g1);
          atomicAdd(&G[curb * NU + c0 + 2], g2);
          atomicAdd(&G[curb * NU + c0 + 3], g3);
          g0 = g1 = g2 = g3 = 0.f;
        }
        curb = b;
      }
      float wi = (float)(win >> 4), wj = (float)(win & 15);
      float dx = cx - wi;
      float ex = hs * __expf(-dx * dx * 0.125f);
      float dy0 = (float)((c0    ) & 15) - wj;
      float dy1 = (float)((c0 + 1) & 15) - wj;
      float dy2 = (float)((c0 + 2) & 15) - wj;
      float dy3 = (float)((c0 + 3) & 15) - wj;
      g0 += ex * __expf(-dy0 * dy0 * 0.125f);
      g1 += ex * __expf(-dy1 * dy1 * 0.125f);
      g2 += ex * __expf(-dy2 * dy2 * 0.125f);
      g3 += ex * __expf(-dy3 * dy3 * 0.125f);
    }
  }
  if (curb >= 0){
    atomicAdd(&G[curb * NU + c0    ], g0);
    atomicAdd(&G[curb * NU + c0 + 1], g1);
    atomicAdd(&G[curb * NU + c0 + 2], g2);
    atomicAdd(&G[curb * NU + c0 + 3], g3);
  }
}

// Aggregation over int4 table: 16-lane group owns one node; lane loads 4 B
// (one 64-B line per row). Integer nibble accumulation in u16-packed regs,
// then static 16-lane permute to standard feature ownership.
// Lane ln's u32 covers bytes ln*4..ln*4+3 = feats {ln*4+q} (lo) and {+64} (hi).
__global__ __launch_bounds__(256) void k_agg(
    const unsigned char* __restrict__ h4, const float* __restrict__ dinv,
    const int* __restrict__ cnt, const ushort* __restrict__ col,
    const float* __restrict__ bias,
    unsigned char* __restrict__ h8c, int cOff,
    float* __restrict__ hh, int first){
  const int lane = threadIdx.x & 63, w = threadIdx.x >> 6;
  const int g = lane >> 4, ln = lane & 15;
  const int n = (blockIdx.x * 4 + w) * 4 + g;       // 3125 blocks x 16 nodes
  if (n >= NN) return;

  // col list: one 8B load/lane covers the group's 64 entries
  ushort4 colv = *reinterpret_cast<const ushort4*>(col + (size_t)n * MAXDEG + ln * 4);
  unsigned u0 = (unsigned)colv.x | ((unsigned)colv.y << 16);
  unsigned u1 = (unsigned)colv.z | ((unsigned)colv.w << 16);

  unsigned s0 = 0, s1 = 0, s2 = 0, s3 = 0;
  {   // self row
    unsigned u = *reinterpret_cast<const unsigned*>(h4 + (size_t)n * 64 + ln * 4);
    s0 += u & 0x000F000Fu;
    s1 += (u >> 8) & 0x000F000Fu;
    s2 += (u >> 4) & 0x000F000Fu;
    s3 += (u >> 12) & 0x000F000Fu;
  }
  int ne = cnt[n]; if (ne > MAXDEG) ne = MAXDEG;
  int nbp = (ne + 15) >> 4; if (nbp > 4) nbp = 4;
  #pragma unroll
  for (int b = 0; b < 4; ++b){
    const int j0 = b * 16;
    if (j0 < ne){
      unsigned r[16]; unsigned okm[16];
      #pragma unroll
      for (int q = 0; q < 16; ++q){
        int i = j0 + q;
        int sl = (g << 4) + (i >> 2);
        unsigned uu = __shfl((q & 2) ? u1 : u0, sl);
        unsigned sidx = (q & 1) ? (uu >> 16) : (uu & 0xffffu);
        bool ok = (i < ne);
        okm[q] = ok ? 0xffffffffu : 0u;
        unsigned srow = ok ? sidx : (unsigned)n;
        r[q] = *reinterpret_cast<const unsigned*>(h4 + (size_t)srow * 64 + ln * 4);
      }
      #pragma unroll
      for (int q = 0; q < 16; ++q){
        unsigned u = (r[q] & okm[q]) | (0x88888888u & ~okm[q]);
        s0 += u & 0x000F000Fu;
        s1 += (u >> 8) & 0x000F000Fu;
        s2 += (u >> 4) & 0x000F000Fu;
        s3 += (u >> 12) & 0x000F000Fu;
      }
    }
  }
  // finalize: sum_v = S/8 - R  (excess-8, scale 1/8), R = rows incl. pads
  float cntT = (float)(1 + nbp * 16);
  float vlo[4], vhi[4];
  vlo[0] = 0.125f * (float)(s0 & 0xffffu) - cntT;
  vlo[1] = 0.125f * (float)(s1 & 0xffffu) - cntT;
  vlo[2] = 0.125f * (float)(s0 >> 16)     - cntT;
  vlo[3] = 0.125f * (float)(s1 >> 16)     - cntT;
  vhi[0] = 0.125f * (float)(s2 & 0xffffu) - cntT;
  vhi[1] = 0.125f * (float)(s3 & 0xffffu) - cntT;
  vhi[2] = 0.125f * (float)(s2 >> 16)     - cntT;
  vhi[3] = 0.125f * (float)(s3 >> 16)     - cntT;

  // permute: target lane t owns feats t*8+k; src lane 2*(t&7)+(k>>2), slot k&3;
  // lo-set for t<8, hi-set for t>=8.
  float vv[8];
  #pragma unroll
  for (int k = 0; k < 8; ++k){
    int gsrc = (lane & 48) | (((ln & 7) << 1) + (k >> 2));
    float rlo = __shfl(vlo[k & 3], gsrc);
    float rhi = __shfl(vhi[k & 3], gsrc);
    vv[k] = (ln < 8) ? rlo : rhi;
  }
  const int fi = ln * 8;
  float di = dinv[n];
  float ssq = 0.f;
  #pragma unroll
  for (int k = 0; k < 8; ++k){
    float v = vv[k] * di + bias[fi + k];
    v = v > 0.f ? v : 0.01f * v;
    ssq += v * v;
    vv[k] = v;
  }
  int pa = __builtin_amdgcn_cvt_pk_fp8_f32(vv[0], vv[1], 0, false);
  pa = __builtin_amdgcn_cvt_pk_fp8_f32(vv[2], vv[3], pa, true);
  int pb = __builtin_amdgcn_cvt_pk_fp8_f32(vv[4], vv[5], 0, false);
  pb = __builtin_amdgcn_cvt_pk_fp8_f32(vv[6], vv[7], pb, true);
  uint2 pk; pk.x = (unsigned)pa; pk.y = (unsigned)pb;
  *reinterpret_cast<uint2*>(h8c + (size_t)n * LDH + cOff + fi) = pk;
  #pragma unroll
  for (int m = 1; m < 16; m <<= 1) ssq += __shfl_xor(ssq, m);
  if (ln == 0){
    if (first) hh[n] = ssq;
    else       hh[n] += ssq;
  }
}

__global__ void k_out(const float* __restrict__ G, const float* __restrict__ lw,
                      const float* __restrict__ lb, float* __restrict__ out){
  int b = blockIdx.x, lane = threadIdx.x;
  float s = 0.f;
  #pragma unroll
  for (int j = 0; j < 4; ++j) s += G[b * NU + lane * 4 + j] * lw[lane * 4 + j];
  #pragma unroll
  for (int o = 32; o; o >>= 1) s += __shfl_down(s, o);
  if (lane == 0) out[b] = 1.f / (1.f + __expf(-(s + lb[0])));
}

extern "C" void kernel_launch(void* const* d_in, const int* in_sizes, int n_in,
                              void* d_out, int out_size, void* d_ws, size_t ws_size,
                              hipStream_t stream){
  const float* x   = (const float*)d_in[0];
  const int*   ei  = (const int*)d_in[1];
  const int*   bat = (const int*)d_in[2];
  const float* W1  = (const float*)d_in[3];
  const float* b1  = (const float*)d_in[4];
  const float* W2  = (const float*)d_in[5];
  const float* b2  = (const float*)d_in[6];
  const float* W3  = (const float*)d_in[7];
  const float* b3  = (const float*)d_in[8];
  const float* S   = (const float*)d_in[9];
  const float* lw  = (const float*)d_in[10];
  const float* lb  = (const float*)d_in[11];
  float* out = (float*)d_out;
  char* w = (char*)d_ws;

  int*      pos  = (int*)     (w + OFF_POS);
  float*    G    = (float*)   (w + OFF_G);
  int*      cnt  = (int*)     (w + OFF_CNT);
  unsigned* be   = (unsigned*)(w + OFF_BE);
  ushort*   col  = (ushort*)  (w + OFF_COL);
  float*    dinv = (float*)   (w + OFF_DINV);
  unsigned char* x8  = (unsigned char*)(w + OFF_X8);
  unsigned char* h4  = (unsigned char*)(w + OFF_H4);
  unsigned char* h8c = (unsigned char*)(w + OFF_H8C);
  float*    hh   = (float*)   (w + OFF_HH);
  unsigned char* w8r = (unsigned char*)(w + OFF_W8R);
  unsigned char* sbr = (unsigned char*)(w + OFF_SBR);
  float*    ss   = (float*)   (w + OFF_SS);

  hipMemsetAsync(w, 0, 66048, stream);                      // pos + G

  k_pb<<<6798, 256, 0, stream>>>(ei, pos, be, x, (unsigned*)x8, S, (unsigned*)sbr,
                                 W1, W2, W3, w8r, ss);
  k_build<<<NB, 256, 0, stream>>>(pos, be, cnt, col, dinv);

  dim3 blk(256);
  // layer 1
  k_gemm8<<<391, blk, 0, stream>>>(x8, FD, w8r, h4, dinv);
  k_agg<<<3125, 256, 0, stream>>>(h4, dinv, cnt, col, b1, h8c, 0, hh, 1);
  // layer 2 (A = h8c[:,0:128))
  k_gemm8<<<391, blk, 0, stream>>>(h8c, LDH, w8r + 16384, h4, dinv);
  k_agg<<<3125, 256, 0, stream>>>(h4, dinv, cnt, col, b2, h8c, 128, hh, 0);
  // layer 3 (A = h8c[:,128:256))
  k_gemm8<<<391, blk, 0, stream>>>(h8c + 128, LDH, w8r + 32768, h4, dinv);
  k_agg<<<3125, 256, 0, stream>>>(h4, dinv, cnt, col, b3, h8c, 256, hh, 0);

  // wave-autonomous fused SOM
  k_gsom<<<391, blk, 0, stream>>>(h8c, sbr, ss, hh, bat, G, NN);
  k_out<<<64, 64, 0, stream>>>(G, lw, lb, out);
}